// Round 1
// baseline (1627.137 us; speedup 1.0000x reference)
//
#include <hip/hip_runtime.h>

#define L_ 4
#define H_ 8
#define Nn 1024
#define F_ 128
#define E_ 128
#define FF_ 512
#define OUT_ 64
#define B_ 32

// ---------------- GEMM TN: C[m,n] = sum_k A[k*lda+m] * B[k*ldb+n] ----------------
// tiles 64x64, K_TILE=32, 256 threads (16x16), 4x4 per thread. All dims divide exactly.
__global__ __launch_bounds__(256) void k_gemm_tn(
    const float* __restrict__ A, int lda, long sAz,
    const float* __restrict__ B, int ldb, long sBz,
    float* __restrict__ C, int ldc, long sCz, int K)
{
    A += (long)blockIdx.z * sAz;
    B += (long)blockIdx.z * sBz;
    C += (long)blockIdx.z * sCz;
    __shared__ float As[32][64];
    __shared__ float Bs[32][64];
    const int t = threadIdx.x;
    const int txn = t & 15, tym = t >> 4;
    const int m0 = blockIdx.x * 64, n0 = blockIdx.y * 64;
    float acc[4][4] = {};
    for (int k0 = 0; k0 < K; k0 += 32) {
#pragma unroll
        for (int r = 0; r < 2; ++r) {
            int s = t + r * 256;                 // 512 float4 slots
            int kk = s >> 4, c4 = (s & 15) << 2;
            *reinterpret_cast<float4*>(&As[kk][c4]) =
                *reinterpret_cast<const float4*>(&A[(long)(k0 + kk) * lda + m0 + c4]);
            *reinterpret_cast<float4*>(&Bs[kk][c4]) =
                *reinterpret_cast<const float4*>(&B[(long)(k0 + kk) * ldb + n0 + c4]);
        }
        __syncthreads();
#pragma unroll
        for (int kk = 0; kk < 32; ++kk) {
            float4 a4 = *reinterpret_cast<const float4*>(&As[kk][tym << 2]);
            float4 b4 = *reinterpret_cast<const float4*>(&Bs[kk][txn << 2]);
            float av[4] = {a4.x, a4.y, a4.z, a4.w};
            float bv[4] = {b4.x, b4.y, b4.z, b4.w};
#pragma unroll
            for (int i = 0; i < 4; ++i)
#pragma unroll
                for (int j = 0; j < 4; ++j) acc[i][j] += av[i] * bv[j];
        }
        __syncthreads();
    }
#pragma unroll
    for (int i = 0; i < 4; ++i) {
        float4 v = make_float4(acc[i][0], acc[i][1], acc[i][2], acc[i][3]);
        *reinterpret_cast<float4*>(&C[(long)(m0 + (tym << 2) + i) * ldc + n0 + (txn << 2)]) = v;
    }
}

// ---------------- GEMM NT: C[m,n] = sum_k A[m*K+k] * B[n*K+k] (+bias, opt relu) ------
template <int RELU>
__global__ __launch_bounds__(256) void k_gemm_nt(
    const float* __restrict__ A, const float* __restrict__ B,
    const float* __restrict__ bias, float* __restrict__ C, int K, int ldc)
{
    __shared__ float As[32][64];
    __shared__ float Bs[32][64];
    const int t = threadIdx.x;
    const int txn = t & 15, tym = t >> 4;
    const int m0 = blockIdx.x * 64, n0 = blockIdx.y * 64;
    float acc[4][4] = {};
    for (int k0 = 0; k0 < K; k0 += 32) {
#pragma unroll
        for (int r = 0; r < 2; ++r) {
            int s = t + r * 256;                 // 512 float4 slots
            int row = s >> 3, kq = (s & 7) << 2; // 8 float4 per 32-wide K strip
            float4 av = *reinterpret_cast<const float4*>(&A[(long)(m0 + row) * K + k0 + kq]);
            As[kq + 0][row] = av.x; As[kq + 1][row] = av.y;
            As[kq + 2][row] = av.z; As[kq + 3][row] = av.w;
            float4 bv = *reinterpret_cast<const float4*>(&B[(long)(n0 + row) * K + k0 + kq]);
            Bs[kq + 0][row] = bv.x; Bs[kq + 1][row] = bv.y;
            Bs[kq + 2][row] = bv.z; Bs[kq + 3][row] = bv.w;
        }
        __syncthreads();
#pragma unroll
        for (int kk = 0; kk < 32; ++kk) {
            float4 a4 = *reinterpret_cast<const float4*>(&As[kk][tym << 2]);
            float4 b4 = *reinterpret_cast<const float4*>(&Bs[kk][txn << 2]);
            float av[4] = {a4.x, a4.y, a4.z, a4.w};
            float bv[4] = {b4.x, b4.y, b4.z, b4.w};
#pragma unroll
            for (int i = 0; i < 4; ++i)
#pragma unroll
                for (int j = 0; j < 4; ++j) acc[i][j] += av[i] * bv[j];
        }
        __syncthreads();
    }
#pragma unroll
    for (int i = 0; i < 4; ++i)
#pragma unroll
        for (int j = 0; j < 4; ++j) {
            float v = acc[i][j] + bias[n0 + (txn << 2) + j];
            if (RELU) v = fmaxf(v, 0.f);
            C[(long)(m0 + (tym << 2) + i) * ldc + n0 + (txn << 2) + j] = v;
        }
}

// ---------------- small kernels ----------------
__global__ void k_mask(const int* __restrict__ adj, float* __restrict__ maskF)
{
    long i = (long)blockIdx.x * 256 + threadIdx.x;
    maskF[i] = adj[i] > 0 ? 1.f : 0.f;
}

__global__ void k_deg(const float* __restrict__ maskF, float* __restrict__ deg)
{
    int n = blockIdx.x * 256 + threadIdx.x;
    float s = 0.f;
    for (int j = 0; j < Nn; ++j) s += maskF[(long)j * Nn + n];
    deg[n] = s;
}

__global__ void k_xs(const float* __restrict__ x, float* __restrict__ xs)
{
    int i = blockIdx.x * 256 + threadIdx.x; // B*F
    int b = i >> 7, f = i & 127;
    const float* p = x + (long)b * Nn * F_ + f;
    float s = 0.f;
    for (int n = 0; n < Nn; ++n) s += p[(long)n * F_];
    xs[i] = s;
}

__global__ void k_hsum(const float* __restrict__ xs, const float* __restrict__ Wl,
                       const float* __restrict__ bsl, float* __restrict__ hsum)
{
    int i = blockIdx.x * 256 + threadIdx.x; // B*H*E, e inner
    int e = i & 127, h = (i >> 7) & 7, b = i >> 10;
    const float* w = Wl + ((long)h * E_ + e) * F_;
    const float* xb = xs + b * F_;
    float s = 0.f;
    for (int f = 0; f < F_; ++f) s += xb[f] * w[f];
    hsum[i] = s + (float)Nn * bsl[h * E_ + e];
}

__global__ void k_d12(const float* __restrict__ Asl, const float* __restrict__ bsl,
                      float* __restrict__ d12)
{
    int i = blockIdx.x * 256 + threadIdx.x; // 2*H*N
    int n = i & 1023, h = (i >> 10) & 7, w = i >> 13;
    const float* a = Asl + ((long)h * 2 * E_ + (long)w * E_) * Nn + n;
    const float* bb = bsl + h * E_;
    float s = 0.f;
    for (int e = 0; e < E_; ++e) s += bb[e] * a[(long)e * Nn];
    d12[((long)w * H_ + h) * Nn + n] = s;
}

// score[b,h,n] = x[b,n,:].C1t[h,n,:] + y[b,n,:].C2t[h,n,:] + d1[h,n] + deg[n]*d2[h,n]
__global__ __launch_bounds__(64) void k_score(
    const float* __restrict__ x, const float* __restrict__ y,
    const float* __restrict__ C1t, const float* __restrict__ C2t,
    const float* __restrict__ d12, const float* __restrict__ deg,
    float* __restrict__ score)
{
    const int n = blockIdx.x, h = blockIdx.y, t = threadIdx.x;
    const long cb = ((long)h * Nn + n) * F_;
    const float c1a = C1t[cb + t], c1b = C1t[cb + t + 64];
    const float c2a = C2t[cb + t], c2b = C2t[cb + t + 64];
    const float sb = d12[(long)h * Nn + n] + deg[n] * d12[((long)H_ + h) * Nn + n];
    for (int b = 0; b < B_; ++b) {
        const long base = ((long)b * Nn + n) * F_;
        float p = x[base + t] * c1a + x[base + t + 64] * c1b +
                  y[base + t] * c2a + y[base + t + 64] * c2b;
#pragma unroll
        for (int o = 32; o; o >>= 1) p += __shfl_xor(p, o);
        if (t == 0) score[((long)b * H_ + h) * Nn + n] = p + sb;
    }
}

// att + residual + LN1, in place on x. One wave per (b,n) row.
__global__ __launch_bounds__(64) void k_attn_ln1(
    float* __restrict__ x, const float* __restrict__ score,
    const float* __restrict__ hsum, const float* __restrict__ g,
    const float* __restrict__ be)
{
    const int n = blockIdx.x, b = blockIdx.y, t = threadIdx.x;
    const long xbase = ((long)b * Nn + n) * F_;
    float v0 = x[xbase + t], v1 = x[xbase + t + 64];
    float a0 = 0.f, a1 = 0.f;
#pragma unroll
    for (int h = 0; h < H_; ++h) {
        float s = score[((long)b * H_ + h) * Nn + n];
        float h0 = hsum[((long)b * H_ + h) * E_ + t];
        float h1 = hsum[((long)b * H_ + h) * E_ + t + 64];
        float p0 = s * h0, p1 = s * h1;
        a0 += (p0 > 0.f ? p0 : 0.01f * p0);
        a1 += (p1 > 0.f ? p1 : 0.01f * p1);
    }
    v0 += a0; v1 += a1;
    float sum = v0 + v1;
#pragma unroll
    for (int o = 32; o; o >>= 1) sum += __shfl_xor(sum, o);
    const float mean = sum * (1.f / 128.f);
    const float d0 = v0 - mean, d1 = v1 - mean;
    float vs = d0 * d0 + d1 * d1;
#pragma unroll
    for (int o = 32; o; o >>= 1) vs += __shfl_xor(vs, o);
    const float rstd = rsqrtf(vs * (1.f / 128.f) + 1e-5f);
    x[xbase + t]      = d0 * rstd * g[t] + be[t];
    x[xbase + t + 64] = d1 * rstd * g[t + 64] + be[t + 64];
}

// residual + LN2, in place on x (ffo = FF output).
__global__ __launch_bounds__(64) void k_ln2(
    float* __restrict__ x, const float* __restrict__ ffo,
    const float* __restrict__ g, const float* __restrict__ be)
{
    const int n = blockIdx.x, b = blockIdx.y, t = threadIdx.x;
    const long xbase = ((long)b * Nn + n) * F_;
    float v0 = x[xbase + t] + ffo[xbase + t];
    float v1 = x[xbase + t + 64] + ffo[xbase + t + 64];
    float sum = v0 + v1;
#pragma unroll
    for (int o = 32; o; o >>= 1) sum += __shfl_xor(sum, o);
    const float mean = sum * (1.f / 128.f);
    const float d0 = v0 - mean, d1 = v1 - mean;
    float vs = d0 * d0 + d1 * d1;
#pragma unroll
    for (int o = 32; o; o >>= 1) vs += __shfl_xor(vs, o);
    const float rstd = rsqrtf(vs * (1.f / 128.f) + 1e-5f);
    x[xbase + t]      = d0 * rstd * g[t] + be[t];
    x[xbase + t + 64] = d1 * rstd * g[t + 64] + be[t + 64];
}

// Final projection: partial sums over 256-wide K chunks (deterministic, no atomics)
__global__ __launch_bounds__(256) void k_final_partial(
    const float* __restrict__ x, const float* __restrict__ Wo,
    float* __restrict__ part)
{
    const int c = blockIdx.x;      // 512 chunks of 256 K
    const int k0 = c * 256;
    __shared__ float xk[B_][256];
    __shared__ float woT[256][OUT_ + 1];
    const int t = threadIdx.x;
#pragma unroll
    for (int r = 0; r < 8; ++r) {  // stage relu(x): 2048 float4 slots
        int s = t + r * 256;
        int b = s >> 6, kq = (s & 63) << 2;
        float4 v = *reinterpret_cast<const float4*>(&x[(long)b * (Nn * F_) + k0 + kq]);
        v.x = fmaxf(v.x, 0.f); v.y = fmaxf(v.y, 0.f);
        v.z = fmaxf(v.z, 0.f); v.w = fmaxf(v.w, 0.f);
        *reinterpret_cast<float4*>(&xk[b][kq]) = v;
    }
#pragma unroll
    for (int r = 0; r < 16; ++r) { // stage Wo transposed: 4096 float4 slots
        int s = t + r * 256;
        int o = s >> 6, kq = (s & 63) << 2;
        float4 v = *reinterpret_cast<const float4*>(&Wo[(long)o * (Nn * F_) + k0 + kq]);
        woT[kq + 0][o] = v.x; woT[kq + 1][o] = v.y;
        woT[kq + 2][o] = v.z; woT[kq + 3][o] = v.w;
    }
    __syncthreads();
    const int o = t & 63, bg = t >> 6; // 4 groups of 8 batches
    float acc[8] = {};
    for (int k = 0; k < 256; ++k) {
        float w = woT[k][o];
#pragma unroll
        for (int i = 0; i < 8; ++i) acc[i] += xk[bg * 8 + i][k] * w;
    }
#pragma unroll
    for (int i = 0; i < 8; ++i)
        part[((long)c * B_ + bg * 8 + i) * OUT_ + o] = acc[i];
}

__global__ void k_final_reduce(const float* __restrict__ part,
                               const float* __restrict__ bo, float* __restrict__ out)
{
    int i = blockIdx.x * 256 + threadIdx.x; // B*OUT = 2048
    int o = i & 63;
    float s = bo[o];
    for (int c = 0; c < 512; ++c) s += part[(long)c * (B_ * OUT_) + i];
    out[i] = s;
}

extern "C" void kernel_launch(void* const* d_in, const int* in_sizes, int n_in,
                              void* d_out, int out_size, void* d_ws, size_t ws_size,
                              hipStream_t stream)
{
    const float* x_in = (const float*)d_in[0];
    const int*   adj  = (const int*)d_in[1];
    const float* Ws   = (const float*)d_in[2];
    const float* bs   = (const float*)d_in[3];
    const float* As   = (const float*)d_in[4];
    const float* W1   = (const float*)d_in[5];
    const float* b1   = (const float*)d_in[6];
    const float* W2   = (const float*)d_in[7];
    const float* b2   = (const float*)d_in[8];
    const float* g1   = (const float*)d_in[9];
    const float* be1  = (const float*)d_in[10];
    const float* g2   = (const float*)d_in[11];
    const float* be2  = (const float*)d_in[12];
    const float* Wo   = (const float*)d_in[13];
    const float* bo   = (const float*)d_in[14];
    float* out = (float*)d_out;

    float* p = (float*)d_ws;
    float* maskF = p; p += (long)Nn * Nn;
    float* deg   = p; p += Nn;
    float* xc    = p; p += (long)B_ * Nn * F_;
    float* y     = p; p += (long)B_ * Nn * F_;   // also reused as FF output
    float* T     = p; p += (long)8192 * FF_;     // FF1 intermediate, 8192-row chunks
    float* C1t   = p; p += (long)H_ * Nn * F_;
    float* C2t   = p; p += (long)H_ * Nn * F_;
    float* d12   = p; p += 2 * H_ * Nn;
    float* xsb   = p; p += B_ * F_;
    float* hsum  = p; p += B_ * H_ * E_;
    float* score = p; p += (long)B_ * H_ * Nn;
    float* part  = p; p += (long)512 * B_ * OUT_;

    hipMemcpyAsync(xc, x_in, sizeof(float) * (long)B_ * Nn * F_,
                   hipMemcpyDeviceToDevice, stream);
    k_mask<<<(Nn * Nn) / 256, 256, 0, stream>>>(adj, maskF);
    k_deg<<<Nn / 256, 256, 0, stream>>>(maskF, deg);

    for (int l = 0; l < L_; ++l) {
        const float* Wl  = Ws + (long)l * H_ * E_ * F_;
        const float* bsl = bs + (long)l * H_ * E_;
        const float* Asl = As + (long)l * H_ * 2 * E_ * Nn;
        const float* W1l = W1 + (long)l * FF_ * F_;
        const float* b1l = b1 + (long)l * FF_;
        const float* W2l = W2 + (long)l * F_ * FF_;
        const float* b2l = b2 + (long)l * F_;

        // C1t[h][n][f] = sum_e As[l,h,e,n] * Ws[l,h,e,f]; C2t likewise with e+E
        k_gemm_tn<<<dim3(16, 2, 8), 256, 0, stream>>>(
            Asl, Nn, (long)2 * E_ * Nn, Wl, F_, (long)E_ * F_,
            C1t, F_, (long)Nn * F_, E_);
        k_gemm_tn<<<dim3(16, 2, 8), 256, 0, stream>>>(
            Asl + (long)E_ * Nn, Nn, (long)2 * E_ * Nn, Wl, F_, (long)E_ * F_,
            C2t, F_, (long)Nn * F_, E_);
        // y[b][n][f] = sum_j maskF[j][n] * x[b][j][f]
        k_gemm_tn<<<dim3(16, 2, 32), 256, 0, stream>>>(
            maskF, Nn, 0L, xc, F_, (long)Nn * F_,
            y, F_, (long)Nn * F_, Nn);

        k_xs<<<(B_ * F_) / 256, 256, 0, stream>>>(xc, xsb);
        k_hsum<<<(B_ * H_ * E_) / 256, 256, 0, stream>>>(xsb, Wl, bsl, hsum);
        k_d12<<<(2 * H_ * Nn) / 256, 256, 0, stream>>>(Asl, bsl, d12);
        k_score<<<dim3(Nn, H_), 64, 0, stream>>>(xc, y, C1t, C2t, d12, deg, score);
        k_attn_ln1<<<dim3(Nn, B_), 64, 0, stream>>>(xc, score, hsum,
                                                    g1 + l * F_, be1 + l * F_);
        // FF in 4 chunks of 8192 rows (keeps T at 16 MB)
        for (int cb = 0; cb < 4; ++cb) {
            const long r0 = (long)cb * 8192;
            k_gemm_nt<1><<<dim3(128, 8), 256, 0, stream>>>(
                xc + r0 * F_, W1l, b1l, T, F_, FF_);
            k_gemm_nt<0><<<dim3(128, 2), 256, 0, stream>>>(
                T, W2l, b2l, y + r0 * F_, FF_, F_);
        }
        k_ln2<<<dim3(Nn, B_), 64, 0, stream>>>(xc, y, g2 + l * F_, be2 + l * F_);
    }

    k_final_partial<<<512, 256, 0, stream>>>(xc, Wo, part);
    k_final_reduce<<<(B_ * OUT_) / 256, 256, 0, stream>>>(part, bo, out);
}

// Round 2
// 808.124 us; speedup vs baseline: 2.0135x; 2.0135x over previous
//
#include <hip/hip_runtime.h>

#define L_ 4
#define H_ 8
#define Nn 1024
#define F_ 128
#define E_ 128
#define FF_ 512
#define OUT_ 64
#define B_ 32

typedef unsigned short u16;
typedef __bf16 bf16_t;
typedef __attribute__((ext_vector_type(8))) __bf16 bf16x8;
typedef __attribute__((ext_vector_type(4))) float f32x4;

__device__ __forceinline__ u16 f2b(float v) {
    bf16_t h = (bf16_t)v;
    return __builtin_bit_cast(u16, h);
}

// ============ bf16 MFMA GEMM (NT): C[m,n] = sum_k A[m,k]*B[n,k] ============
// A,B bf16 row-major K-contiguous. BMx128 tile, BK=64, 256 thr.
// DUAL: second B operand (lo part) accumulated into same C.
// EPI: 0 plain fp32 out; 1 bias+relu -> bf16 out; 2 bias -> fp32 out.
template <int BM, bool DUAL, int EPI>
__global__ __launch_bounds__(256) void k_mfma(
    const u16* __restrict__ A, int lda, long sAz,
    const u16* __restrict__ Bhp, const u16* __restrict__ Blp, int ldb, long sBz,
    const float* __restrict__ bias,
    float* __restrict__ Cf, u16* __restrict__ Cb, int ldc, long sCz, int K)
{
    constexpr int NF = (BM == 128) ? 4 : 2;
    constexpr int AIT = BM / 32;  // A staging iters (BM*8 chunks / 256 thr)
    __shared__ __align__(16) u16 lds[BM * 64 + (DUAL ? 2 : 1) * 128 * 64];
    u16* Al = lds;
    u16* Bh = lds + BM * 64;
    u16* Bl = Bh + 128 * 64;
    const int t = threadIdx.x;
    const int w = t >> 6, l = t & 63, lr = l & 15, lg = l >> 4;
    const int wm0 = (BM == 128) ? (w >> 1) * 64 : 0;
    const int wn0 = (BM == 128) ? (w & 1) * 64 : w * 32;
    const int m0 = blockIdx.x * BM, n0 = blockIdx.y * 128;
    A += (long)blockIdx.z * sAz;
    Bhp += (long)blockIdx.z * sBz;
    if (DUAL) Blp += (long)blockIdx.z * sBz;

    f32x4 acc[4][NF] = {};

    for (int k0 = 0; k0 < K; k0 += 64) {
        __syncthreads();
#pragma unroll
        for (int i = 0; i < AIT; ++i) {
            int ch = i * 256 + t, row = ch >> 3, jq = ch & 7;
            *reinterpret_cast<float4*>(&Al[row * 64 + ((jq ^ (row & 7)) << 3)]) =
                *reinterpret_cast<const float4*>(&A[(long)(m0 + row) * lda + k0 + (jq << 3)]);
        }
#pragma unroll
        for (int i = 0; i < 4; ++i) {
            int ch = i * 256 + t, row = ch >> 3, jq = ch & 7;
            int dst = row * 64 + ((jq ^ (row & 7)) << 3);
            long src = (long)(n0 + row) * ldb + k0 + (jq << 3);
            *reinterpret_cast<float4*>(&Bh[dst]) = *reinterpret_cast<const float4*>(&Bhp[src]);
            if (DUAL)
                *reinterpret_cast<float4*>(&Bl[dst]) = *reinterpret_cast<const float4*>(&Blp[src]);
        }
        __syncthreads();
#pragma unroll
        for (int ks = 0; ks < 2; ++ks) {
            bf16x8 af[4], bh[NF], bl[NF];
            const int kq = ks * 4 + lg;
#pragma unroll
            for (int mf = 0; mf < 4; ++mf) {
                int row = wm0 + mf * 16 + lr;
                af[mf] = *reinterpret_cast<const bf16x8*>(&Al[row * 64 + ((kq ^ (row & 7)) << 3)]);
            }
#pragma unroll
            for (int nf = 0; nf < NF; ++nf) {
                int row = wn0 + nf * 16 + lr;
                int off = row * 64 + ((kq ^ (row & 7)) << 3);
                bh[nf] = *reinterpret_cast<const bf16x8*>(&Bh[off]);
                if (DUAL) bl[nf] = *reinterpret_cast<const bf16x8*>(&Bl[off]);
            }
#pragma unroll
            for (int mf = 0; mf < 4; ++mf)
#pragma unroll
                for (int nf = 0; nf < NF; ++nf) {
                    acc[mf][nf] = __builtin_amdgcn_mfma_f32_16x16x32_bf16(af[mf], bh[nf], acc[mf][nf], 0, 0, 0);
                    if (DUAL)
                        acc[mf][nf] = __builtin_amdgcn_mfma_f32_16x16x32_bf16(af[mf], bl[nf], acc[mf][nf], 0, 0, 0);
                }
        }
    }

    float bv[NF];
    if (EPI) {
#pragma unroll
        for (int nf = 0; nf < NF; ++nf) bv[nf] = bias[n0 + wn0 + nf * 16 + lr];
    }
    if (EPI == 1) Cb += (long)blockIdx.z * sCz;
    else          Cf += (long)blockIdx.z * sCz;
#pragma unroll
    for (int mf = 0; mf < 4; ++mf)
#pragma unroll
        for (int nf = 0; nf < NF; ++nf)
#pragma unroll
            for (int r = 0; r < 4; ++r) {
                long row = m0 + wm0 + mf * 16 + lg * 4 + r;
                int col = n0 + wn0 + nf * 16 + lr;
                float v = acc[mf][nf][r];
                if (EPI) v += bv[nf];
                if (EPI == 1) Cb[row * ldc + col] = f2b(fmaxf(v, 0.f));
                else          Cf[row * ldc + col] = v;
            }
}

// ---------------- fp32 GEMM TN (kept for C1t/C2t): C[m,n]=sum_k A[k*lda+m]*B[k*ldb+n]
__global__ __launch_bounds__(256) void k_gemm_tn(
    const float* __restrict__ A, int lda, long sAz,
    const float* __restrict__ B, int ldb, long sBz,
    float* __restrict__ C, int ldc, long sCz, int K)
{
    A += (long)blockIdx.z * sAz;
    B += (long)blockIdx.z * sBz;
    C += (long)blockIdx.z * sCz;
    __shared__ float As[32][64];
    __shared__ float Bs[32][64];
    const int t = threadIdx.x;
    const int txn = t & 15, tym = t >> 4;
    const int m0 = blockIdx.x * 64, n0 = blockIdx.y * 64;
    float acc[4][4] = {};
    for (int k0 = 0; k0 < K; k0 += 32) {
#pragma unroll
        for (int r = 0; r < 2; ++r) {
            int s = t + r * 256;
            int kk = s >> 4, c4 = (s & 15) << 2;
            *reinterpret_cast<float4*>(&As[kk][c4]) =
                *reinterpret_cast<const float4*>(&A[(long)(k0 + kk) * lda + m0 + c4]);
            *reinterpret_cast<float4*>(&Bs[kk][c4]) =
                *reinterpret_cast<const float4*>(&B[(long)(k0 + kk) * ldb + n0 + c4]);
        }
        __syncthreads();
#pragma unroll
        for (int kk = 0; kk < 32; ++kk) {
            float4 a4 = *reinterpret_cast<const float4*>(&As[kk][tym << 2]);
            float4 b4 = *reinterpret_cast<const float4*>(&Bs[kk][txn << 2]);
            float av[4] = {a4.x, a4.y, a4.z, a4.w};
            float bv[4] = {b4.x, b4.y, b4.z, b4.w};
#pragma unroll
            for (int i = 0; i < 4; ++i)
#pragma unroll
                for (int j = 0; j < 4; ++j) acc[i][j] += av[i] * bv[j];
        }
        __syncthreads();
    }
#pragma unroll
    for (int i = 0; i < 4; ++i) {
        float4 v = make_float4(acc[i][0], acc[i][1], acc[i][2], acc[i][3]);
        *reinterpret_cast<float4*>(&C[(long)(m0 + (tym << 2) + i) * ldc + n0 + (txn << 2)]) = v;
    }
}

// ---------------- small kernels ----------------
// maskTb[n][j] = bf16( adj[j][n] > 0 )
__global__ __launch_bounds__(256) void k_maskT(const int* __restrict__ adj, u16* __restrict__ maskTb)
{
    __shared__ u16 tl[64][65];
    const int j0 = blockIdx.x * 64, n0 = blockIdx.y * 64, t = threadIdx.x;
#pragma unroll
    for (int i = 0; i < 16; ++i) {
        int s = i * 256 + t, jl = s >> 6, nl = s & 63;
        tl[jl][nl] = (adj[(long)(j0 + jl) * Nn + n0 + nl] > 0) ? 0x3F80 : 0;
    }
    __syncthreads();
#pragma unroll
    for (int i = 0; i < 16; ++i) {
        int s = i * 256 + t, nl = s >> 6, jl = s & 63;
        maskTb[(long)(n0 + nl) * Nn + j0 + jl] = tl[jl][nl];
    }
}

__global__ void k_degA(const int* __restrict__ adj, float* __restrict__ deg)
{
    int n = blockIdx.x * 256 + threadIdx.x;
    float s = 0.f;
    for (int j = 0; j < Nn; ++j) s += (adj[(long)j * Nn + n] > 0) ? 1.f : 0.f;
    deg[n] = s;
}

__global__ void k_cvtW(const float* __restrict__ W1, const float* __restrict__ W2,
                       u16* __restrict__ W1b, u16* __restrict__ W2b)
{
    int i = blockIdx.x * 256 + threadIdx.x;  // L*FF*F
    W1b[i] = f2b(W1[i]);
    W2b[i] = f2b(W2[i]);
}

// x[b][n][f] fp32 -> xh/xl[b][f][n] bf16 (hi/lo split)
__global__ __launch_bounds__(256) void k_xpose(const float* __restrict__ x,
                                               u16* __restrict__ xh, u16* __restrict__ xl)
{
    __shared__ float tile[64][132];
    const int b = blockIdx.y, n0 = blockIdx.x * 64, t = threadIdx.x;
#pragma unroll
    for (int i = 0; i < 8; ++i) {
        int s = i * 256 + t, nl = s >> 5, f4 = (s & 31) << 2;
        float4 v = *reinterpret_cast<const float4*>(&x[((long)b * Nn + n0 + nl) * F_ + f4]);
        tile[nl][f4] = v.x; tile[nl][f4 + 1] = v.y;
        tile[nl][f4 + 2] = v.z; tile[nl][f4 + 3] = v.w;
    }
    __syncthreads();
    const int f = t >> 1, nb = (t & 1) << 5;
    const long ob = ((long)b * F_ + f) * Nn + n0 + nb;
    union { u16 u[8]; float4 v; } Hv, Lv;
#pragma unroll
    for (int i = 0; i < 32; i += 8) {
#pragma unroll
        for (int j = 0; j < 8; ++j) {
            float v = tile[nb + i + j][f];
            bf16_t h = (bf16_t)v;
            Hv.u[j] = __builtin_bit_cast(u16, h);
            Lv.u[j] = f2b(v - (float)h);
        }
        *reinterpret_cast<float4*>(&xh[ob + i]) = Hv.v;
        *reinterpret_cast<float4*>(&xl[ob + i]) = Lv.v;
    }
}

__global__ void k_xs(const float* __restrict__ x, float* __restrict__ xs)
{
    int i = blockIdx.x * 256 + threadIdx.x;  // B*F
    int b = i >> 7, f = i & 127;
    const float* p = x + (long)b * Nn * F_ + f;
    float s = 0.f;
    for (int n = 0; n < Nn; ++n) s += p[(long)n * F_];
    xs[i] = s;
}

__global__ void k_hsum(const float* __restrict__ xs, const float* __restrict__ Wl,
                       const float* __restrict__ bsl, float* __restrict__ hsum)
{
    int i = blockIdx.x * 256 + threadIdx.x;  // B*H*E
    int e = i & 127, h = (i >> 7) & 7, b = i >> 10;
    const float* w = Wl + ((long)h * E_ + e) * F_;
    const float* xb = xs + b * F_;
    float s = 0.f;
    for (int f = 0; f < F_; ++f) s += xb[f] * w[f];
    hsum[i] = s + (float)Nn * bsl[h * E_ + e];
}

__global__ void k_d12(const float* __restrict__ Asl, const float* __restrict__ bsl,
                      float* __restrict__ d12)
{
    int i = blockIdx.x * 256 + threadIdx.x;  // 2*H*N
    int n = i & 1023, h = (i >> 10) & 7, w = i >> 13;
    const float* a = Asl + ((long)h * 2 * E_ + (long)w * E_) * Nn + n;
    const float* bb = bsl + h * E_;
    float s = 0.f;
    for (int e = 0; e < E_; ++e) s += bb[e] * a[(long)e * Nn];
    d12[((long)w * H_ + h) * Nn + n] = s;
}

// block per node n: stage C1/C2 rows once, waves split batches
__global__ __launch_bounds__(256) void k_score2(
    const float* __restrict__ x, const float* __restrict__ y,
    const float* __restrict__ C1t, const float* __restrict__ C2t,
    const float* __restrict__ d12, const float* __restrict__ deg,
    float* __restrict__ score)
{
    const int n = blockIdx.x, t = threadIdx.x;
    __shared__ float c1[H_][128], c2[H_][128];
#pragma unroll
    for (int i = 0; i < 4; ++i) {
        int s = i * 256 + t, h = s >> 7, f = s & 127;
        c1[h][f] = C1t[((long)h * Nn + n) * F_ + f];
        c2[h][f] = C2t[((long)h * Nn + n) * F_ + f];
    }
    __syncthreads();
    const int w = t >> 6, l = t & 63;
    const float dg = deg[n];
    for (int bi = 0; bi < 8; ++bi) {
        const int b = w * 8 + bi;
        const long base = ((long)b * Nn + n) * F_;
        float x0 = x[base + l], x1 = x[base + l + 64];
        float y0 = y[base + l], y1 = y[base + l + 64];
#pragma unroll
        for (int h = 0; h < H_; ++h) {
            float p = x0 * c1[h][l] + x1 * c1[h][l + 64]
                    + y0 * c2[h][l] + y1 * c2[h][l + 64];
#pragma unroll
            for (int o = 32; o; o >>= 1) p += __shfl_xor(p, o);
            if (l == 0)
                score[((long)b * H_ + h) * Nn + n] =
                    p + d12[(long)h * Nn + n] + dg * d12[(long)(H_ + h) * Nn + n];
        }
    }
}

// att + residual + LN1 in place; also emits bf16 copy xb for FF1
__global__ __launch_bounds__(64) void k_attn_ln1(
    float* __restrict__ x, u16* __restrict__ xb, const float* __restrict__ score,
    const float* __restrict__ hsum, const float* __restrict__ g,
    const float* __restrict__ be)
{
    const int n = blockIdx.x, b = blockIdx.y, t = threadIdx.x;
    const long xbase = ((long)b * Nn + n) * F_;
    float v0 = x[xbase + t], v1 = x[xbase + t + 64];
    float a0 = 0.f, a1 = 0.f;
#pragma unroll
    for (int h = 0; h < H_; ++h) {
        float s = score[((long)b * H_ + h) * Nn + n];
        float h0 = hsum[((long)b * H_ + h) * E_ + t];
        float h1 = hsum[((long)b * H_ + h) * E_ + t + 64];
        float p0 = s * h0, p1 = s * h1;
        a0 += (p0 > 0.f ? p0 : 0.01f * p0);
        a1 += (p1 > 0.f ? p1 : 0.01f * p1);
    }
    v0 += a0; v1 += a1;
    float sum = v0 + v1;
#pragma unroll
    for (int o = 32; o; o >>= 1) sum += __shfl_xor(sum, o);
    const float mean = sum * (1.f / 128.f);
    const float d0 = v0 - mean, d1 = v1 - mean;
    float vs = d0 * d0 + d1 * d1;
#pragma unroll
    for (int o = 32; o; o >>= 1) vs += __shfl_xor(vs, o);
    const float rstd = rsqrtf(vs * (1.f / 128.f) + 1e-5f);
    float o0 = d0 * rstd * g[t] + be[t];
    float o1 = d1 * rstd * g[t + 64] + be[t + 64];
    x[xbase + t] = o0;       x[xbase + t + 64] = o1;
    xb[xbase + t] = f2b(o0); xb[xbase + t + 64] = f2b(o1);
}

__global__ __launch_bounds__(64) void k_ln2(
    float* __restrict__ x, const float* __restrict__ ffo,
    const float* __restrict__ g, const float* __restrict__ be)
{
    const int n = blockIdx.x, b = blockIdx.y, t = threadIdx.x;
    const long xbase = ((long)b * Nn + n) * F_;
    float v0 = x[xbase + t] + ffo[xbase + t];
    float v1 = x[xbase + t + 64] + ffo[xbase + t + 64];
    float sum = v0 + v1;
#pragma unroll
    for (int o = 32; o; o >>= 1) sum += __shfl_xor(sum, o);
    const float mean = sum * (1.f / 128.f);
    const float d0 = v0 - mean, d1 = v1 - mean;
    float vs = d0 * d0 + d1 * d1;
#pragma unroll
    for (int o = 32; o; o >>= 1) vs += __shfl_xor(vs, o);
    const float rstd = rsqrtf(vs * (1.f / 128.f) + 1e-5f);
    x[xbase + t]      = d0 * rstd * g[t] + be[t];
    x[xbase + t + 64] = d1 * rstd * g[t + 64] + be[t + 64];
}

__global__ __launch_bounds__(256) void k_final_partial(
    const float* __restrict__ x, const float* __restrict__ Wo,
    float* __restrict__ part)
{
    const int c = blockIdx.x;
    const int k0 = c * 256;
    __shared__ float xk[B_][256];
    __shared__ float woT[256][OUT_ + 1];
    const int t = threadIdx.x;
#pragma unroll
    for (int r = 0; r < 8; ++r) {
        int s = t + r * 256;
        int b = s >> 6, kq = (s & 63) << 2;
        float4 v = *reinterpret_cast<const float4*>(&x[(long)b * (Nn * F_) + k0 + kq]);
        v.x = fmaxf(v.x, 0.f); v.y = fmaxf(v.y, 0.f);
        v.z = fmaxf(v.z, 0.f); v.w = fmaxf(v.w, 0.f);
        *reinterpret_cast<float4*>(&xk[b][kq]) = v;
    }
#pragma unroll
    for (int r = 0; r < 16; ++r) {
        int s = t + r * 256;
        int o = s >> 6, kq = (s & 63) << 2;
        float4 v = *reinterpret_cast<const float4*>(&Wo[(long)o * (Nn * F_) + k0 + kq]);
        woT[kq + 0][o] = v.x; woT[kq + 1][o] = v.y;
        woT[kq + 2][o] = v.z; woT[kq + 3][o] = v.w;
    }
    __syncthreads();
    const int o = t & 63, bg = t >> 6;
    float acc[8] = {};
    for (int k = 0; k < 256; ++k) {
        float w = woT[k][o];
#pragma unroll
        for (int i = 0; i < 8; ++i) acc[i] += xk[bg * 8 + i][k] * w;
    }
#pragma unroll
    for (int i = 0; i < 8; ++i)
        part[((long)c * B_ + bg * 8 + i) * OUT_ + o] = acc[i];
}

__global__ void k_final_reduce(const float* __restrict__ part,
                               const float* __restrict__ bo, float* __restrict__ out)
{
    int i = blockIdx.x * 256 + threadIdx.x;
    int o = i & 63;
    float s = bo[o];
    for (int c = 0; c < 512; ++c) s += part[(long)c * (B_ * OUT_) + i];
    out[i] = s;
}

extern "C" void kernel_launch(void* const* d_in, const int* in_sizes, int n_in,
                              void* d_out, int out_size, void* d_ws, size_t ws_size,
                              hipStream_t stream)
{
    const float* x_in = (const float*)d_in[0];
    const int*   adj  = (const int*)d_in[1];
    const float* Ws   = (const float*)d_in[2];
    const float* bs   = (const float*)d_in[3];
    const float* As   = (const float*)d_in[4];
    const float* W1   = (const float*)d_in[5];
    const float* b1   = (const float*)d_in[6];
    const float* W2   = (const float*)d_in[7];
    const float* b2   = (const float*)d_in[8];
    const float* g1   = (const float*)d_in[9];
    const float* be1  = (const float*)d_in[10];
    const float* g2   = (const float*)d_in[11];
    const float* be2  = (const float*)d_in[12];
    const float* Wo   = (const float*)d_in[13];
    const float* bo   = (const float*)d_in[14];
    float* out = (float*)d_out;

    char* wsb = (char*)d_ws;
    u16*   maskTb = (u16*)wsb;                        // 2 MB
    float* xc     = (float*)(wsb + (2L << 20));       // 16 MB
    float* y      = (float*)(wsb + (18L << 20));      // 16 MB
    char*  R      = wsb + (34L << 20);                // 16 MB multi-use
    u16*   xTh    = (u16*)R;                          //  8 MB (phase A)
    u16*   xTl    = (u16*)(R + (8L << 20));           //  8 MB (phase A)
    float* score  = (float*)R;                        //  1 MB (after mask GEMM)
    u16*   Tb     = (u16*)R;                          // 16 MB (FF phase)
    float* part   = (float*)R;                        //  4 MB (final)
    float* C1t    = (float*)(wsb + (50L << 20));      //  4 MB
    float* C2t    = (float*)(wsb + (54L << 20));      //  4 MB
    u16*   xb     = (u16*)C1t;                        //  8 MB alias (FF phase)
    char*  S      = wsb + (58L << 20);
    float* deg  = (float*)S;                          // 4 KB
    float* xsb  = (float*)(S + (4L << 10));           // 16 KB
    float* hsum = (float*)(S + (20L << 10));          // 128 KB
    float* d12  = (float*)(S + (148L << 10));         // 64 KB
    u16*   W1b  = (u16*)(S + (212L << 10));           // 512 KB (all layers)
    u16*   W2b  = (u16*)(S + (724L << 10));           // 512 KB

    hipMemcpyAsync(xc, x_in, sizeof(float) * (long)B_ * Nn * F_,
                   hipMemcpyDeviceToDevice, stream);
    k_maskT<<<dim3(16, 16), 256, 0, stream>>>(adj, maskTb);
    k_degA<<<Nn / 256, 256, 0, stream>>>(adj, deg);
    k_cvtW<<<(L_ * FF_ * F_) / 256, 256, 0, stream>>>(W1, W2, W1b, W2b);
    k_xpose<<<dim3(16, B_), 256, 0, stream>>>(xc, xTh, xTl);

    for (int l = 0; l < L_; ++l) {
        const float* Wl  = Ws + (long)l * H_ * E_ * F_;
        const float* bsl = bs + (long)l * H_ * E_;
        const float* Asl = As + (long)l * H_ * 2 * E_ * Nn;

        // C1t/C2t fp32 (small, accuracy-critical)
        k_gemm_tn<<<dim3(16, 2, 8), 256, 0, stream>>>(
            Asl, Nn, (long)2 * E_ * Nn, Wl, F_, (long)E_ * F_,
            C1t, F_, (long)Nn * F_, E_);
        k_gemm_tn<<<dim3(16, 2, 8), 256, 0, stream>>>(
            Asl + (long)E_ * Nn, Nn, (long)2 * E_ * Nn, Wl, F_, (long)E_ * F_,
            C2t, F_, (long)Nn * F_, E_);

        // y[b][n][f] = sum_j mask[j][n] x[b][j][f]  (bf16 MFMA, hi+lo exact split)
        k_mfma<128, true, 0><<<dim3(8, 1, 32), 256, 0, stream>>>(
            maskTb, Nn, 0L, xTh, xTl, Nn, (long)F_ * Nn,
            nullptr, y, nullptr, F_, (long)Nn * F_, Nn);

        k_xs<<<(B_ * F_) / 256, 256, 0, stream>>>(xc, xsb);
        k_hsum<<<(B_ * H_ * E_) / 256, 256, 0, stream>>>(xsb, Wl, bsl, hsum);
        k_d12<<<(2 * H_ * Nn) / 256, 256, 0, stream>>>(Asl, bsl, d12);
        k_score2<<<Nn, 256, 0, stream>>>(xc, y, C1t, C2t, d12, deg, score);
        k_attn_ln1<<<dim3(Nn, B_), 64, 0, stream>>>(xc, xb, score, hsum,
                                                    g1 + l * F_, be1 + l * F_);
        // FF: 2 chunks of 16384 rows; Tb (bf16) lives in R
        for (int c = 0; c < 2; ++c) {
            const long r0 = (long)c * 16384;
            k_mfma<128, false, 1><<<dim3(128, 4), 256, 0, stream>>>(
                xb + r0 * F_, F_, 0L, W1b + (long)l * FF_ * F_, nullptr, F_, 0L,
                b1 + l * FF_, nullptr, Tb, FF_, 0L, F_);
            k_mfma<64, false, 2><<<dim3(256, 1), 256, 0, stream>>>(
                Tb, FF_, 0L, W2b + (long)l * F_ * FF_, nullptr, FF_, 0L,
                b2 + l * F_, y + r0 * F_, nullptr, F_, 0L, FF_);
        }
        k_ln2<<<dim3(Nn, B_), 64, 0, stream>>>(xc, y, g2 + l * F_, be2 + l * F_);
        if (l < L_ - 1)
            k_xpose<<<dim3(16, B_), 256, 0, stream>>>(xc, xTh, xTl);
    }

    k_final_partial<<<512, 256, 0, stream>>>(xc, Wo, part);
    k_final_reduce<<<(B_ * OUT_) / 256, 256, 0, stream>>>(part, bo, out);
}

// Round 3
// 687.531 us; speedup vs baseline: 2.3666x; 1.1754x over previous
//
#include <hip/hip_runtime.h>

#define L_ 4
#define H_ 8
#define Nn 1024
#define F_ 128
#define E_ 128
#define FF_ 512
#define OUT_ 64
#define B_ 32

typedef unsigned short u16;
typedef __bf16 bf16_t;
typedef __attribute__((ext_vector_type(8))) __bf16 bf16x8;
typedef __attribute__((ext_vector_type(4))) float f32x4;

__device__ __forceinline__ u16 f2b(float v) {
    bf16_t h = (bf16_t)v;
    return __builtin_bit_cast(u16, h);
}

// ============ bf16 MFMA GEMM (NT): C[m,n] = sum_k A[m,k]*B[n,k] ============
// A,B bf16 row-major K-contiguous. BMx128 tile, BK=64, 256 thr.
// DUAL: second B operand (lo part) accumulated into same C.
// EPI: 0 plain fp32 out; 1 bias+relu -> bf16 out; 2 bias -> fp32 out.
// GSWAP: batch on blockIdx.x (fastest) so each XCD gets few batches x all mtiles.
template <int BM, bool DUAL, int EPI, bool GSWAP = false>
__global__ __launch_bounds__(256) void k_mfma(
    const u16* __restrict__ A, int lda, long sAz,
    const u16* __restrict__ Bhp, const u16* __restrict__ Blp, int ldb, long sBz,
    const float* __restrict__ bias,
    float* __restrict__ Cf, u16* __restrict__ Cb, int ldc, long sCz, int K)
{
    constexpr int NF = (BM == 128) ? 4 : 2;
    constexpr int AIT = BM / 32;  // A staging iters (BM*8 chunks / 256 thr)
    __shared__ __align__(16) u16 lds[BM * 64 + (DUAL ? 2 : 1) * 128 * 64];
    u16* Al = lds;
    u16* Bh = lds + BM * 64;
    u16* Bl = Bh + 128 * 64;
    const int t = threadIdx.x;
    const int w = t >> 6, l = t & 63, lr = l & 15, lg = l >> 4;
    const int wm0 = (BM == 128) ? (w >> 1) * 64 : 0;
    const int wn0 = (BM == 128) ? (w & 1) * 64 : w * 32;
    const int bidm = GSWAP ? blockIdx.z : blockIdx.x;
    const int bidz = GSWAP ? blockIdx.x : blockIdx.z;
    const int m0 = bidm * BM, n0 = blockIdx.y * 128;
    A += (long)bidz * sAz;
    Bhp += (long)bidz * sBz;
    if (DUAL) Blp += (long)bidz * sBz;

    f32x4 acc[4][NF] = {};

    for (int k0 = 0; k0 < K; k0 += 64) {
        __syncthreads();
#pragma unroll
        for (int i = 0; i < AIT; ++i) {
            int ch = i * 256 + t, row = ch >> 3, jq = ch & 7;
            *reinterpret_cast<float4*>(&Al[row * 64 + ((jq ^ (row & 7)) << 3)]) =
                *reinterpret_cast<const float4*>(&A[(long)(m0 + row) * lda + k0 + (jq << 3)]);
        }
#pragma unroll
        for (int i = 0; i < 4; ++i) {
            int ch = i * 256 + t, row = ch >> 3, jq = ch & 7;
            int dst = row * 64 + ((jq ^ (row & 7)) << 3);
            long src = (long)(n0 + row) * ldb + k0 + (jq << 3);
            *reinterpret_cast<float4*>(&Bh[dst]) = *reinterpret_cast<const float4*>(&Bhp[src]);
            if (DUAL)
                *reinterpret_cast<float4*>(&Bl[dst]) = *reinterpret_cast<const float4*>(&Blp[src]);
        }
        __syncthreads();
#pragma unroll
        for (int ks = 0; ks < 2; ++ks) {
            bf16x8 af[4], bh[NF], bl[NF];
            const int kq = ks * 4 + lg;
#pragma unroll
            for (int mf = 0; mf < 4; ++mf) {
                int row = wm0 + mf * 16 + lr;
                af[mf] = *reinterpret_cast<const bf16x8*>(&Al[row * 64 + ((kq ^ (row & 7)) << 3)]);
            }
#pragma unroll
            for (int nf = 0; nf < NF; ++nf) {
                int row = wn0 + nf * 16 + lr;
                int off = row * 64 + ((kq ^ (row & 7)) << 3);
                bh[nf] = *reinterpret_cast<const bf16x8*>(&Bh[off]);
                if (DUAL) bl[nf] = *reinterpret_cast<const bf16x8*>(&Bl[off]);
            }
#pragma unroll
            for (int mf = 0; mf < 4; ++mf)
#pragma unroll
                for (int nf = 0; nf < NF; ++nf) {
                    acc[mf][nf] = __builtin_amdgcn_mfma_f32_16x16x32_bf16(af[mf], bh[nf], acc[mf][nf], 0, 0, 0);
                    if (DUAL)
                        acc[mf][nf] = __builtin_amdgcn_mfma_f32_16x16x32_bf16(af[mf], bl[nf], acc[mf][nf], 0, 0, 0);
                }
        }
    }

    float bv[NF];
    if (EPI) {
#pragma unroll
        for (int nf = 0; nf < NF; ++nf) bv[nf] = bias[n0 + wn0 + nf * 16 + lr];
    }
    if (EPI == 1) Cb += (long)bidz * sCz;
    else          Cf += (long)bidz * sCz;
#pragma unroll
    for (int mf = 0; mf < 4; ++mf)
#pragma unroll
        for (int nf = 0; nf < NF; ++nf)
#pragma unroll
            for (int r = 0; r < 4; ++r) {
                long row = m0 + wm0 + mf * 16 + lg * 4 + r;
                int col = n0 + wn0 + nf * 16 + lr;
                float v = acc[mf][nf][r];
                if (EPI) v += bv[nf];
                if (EPI == 1) Cb[row * ldc + col] = f2b(fmaxf(v, 0.f));
                else          Cf[row * ldc + col] = v;
            }
}

// ---------------- fp32 GEMM TN: C[m,n]=sum_k A[k*lda+m]*B[k*ldb+n] ----------------
// B advanced by (z>>bzshift)*sBz so one launch can cover C1+C2 (interleaved Ct).
__global__ __launch_bounds__(256) void k_gemm_tn(
    const float* __restrict__ A, int lda, long sAz,
    const float* __restrict__ B, int ldb, long sBz, int bzshift,
    float* __restrict__ C, int ldc, long sCz, int K)
{
    A += (long)blockIdx.z * sAz;
    B += (long)(blockIdx.z >> bzshift) * sBz;
    C += (long)blockIdx.z * sCz;
    __shared__ float As[32][64];
    __shared__ float Bs[32][64];
    const int t = threadIdx.x;
    const int txn = t & 15, tym = t >> 4;
    const int m0 = blockIdx.x * 64, n0 = blockIdx.y * 64;
    float acc[4][4] = {};
    for (int k0 = 0; k0 < K; k0 += 32) {
#pragma unroll
        for (int r = 0; r < 2; ++r) {
            int s = t + r * 256;
            int kk = s >> 4, c4 = (s & 15) << 2;
            *reinterpret_cast<float4*>(&As[kk][c4]) =
                *reinterpret_cast<const float4*>(&A[(long)(k0 + kk) * lda + m0 + c4]);
            *reinterpret_cast<float4*>(&Bs[kk][c4]) =
                *reinterpret_cast<const float4*>(&B[(long)(k0 + kk) * ldb + n0 + c4]);
        }
        __syncthreads();
#pragma unroll
        for (int kk = 0; kk < 32; ++kk) {
            float4 a4 = *reinterpret_cast<const float4*>(&As[kk][tym << 2]);
            float4 b4 = *reinterpret_cast<const float4*>(&Bs[kk][txn << 2]);
            float av[4] = {a4.x, a4.y, a4.z, a4.w};
            float bv[4] = {b4.x, b4.y, b4.z, b4.w};
#pragma unroll
            for (int i = 0; i < 4; ++i)
#pragma unroll
                for (int j = 0; j < 4; ++j) acc[i][j] += av[i] * bv[j];
        }
        __syncthreads();
    }
#pragma unroll
    for (int i = 0; i < 4; ++i) {
        float4 v = make_float4(acc[i][0], acc[i][1], acc[i][2], acc[i][3]);
        *reinterpret_cast<float4*>(&C[(long)(m0 + (tym << 2) + i) * ldc + n0 + (txn << 2)]) = v;
    }
}

// ---------------- small kernels ----------------
// maskTb[n][j] = bf16( adj[j][n] > 0 )
__global__ __launch_bounds__(256) void k_maskT(const int* __restrict__ adj, u16* __restrict__ maskTb)
{
    __shared__ u16 tl[64][65];
    const int j0 = blockIdx.x * 64, n0 = blockIdx.y * 64, t = threadIdx.x;
#pragma unroll
    for (int i = 0; i < 16; ++i) {
        int s = i * 256 + t, jl = s >> 6, nl = s & 63;
        tl[jl][nl] = (adj[(long)(j0 + jl) * Nn + n0 + nl] > 0) ? 0x3F80 : 0;
    }
    __syncthreads();
#pragma unroll
    for (int i = 0; i < 16; ++i) {
        int s = i * 256 + t, nl = s >> 6, jl = s & 63;
        maskTb[(long)(n0 + nl) * Nn + j0 + jl] = tl[jl][nl];
    }
}

// deg[n] = #neighbors; 32 blocks, two-level reduce
__global__ __launch_bounds__(256) void k_degA(const int* __restrict__ adj, float* __restrict__ deg)
{
    __shared__ float sh[8][32];
    const int t = threadIdx.x;
    const int n = blockIdx.x * 32 + (t & 31);
    const int seg = t >> 5;
    float s = 0.f;
    for (int i = 0; i < 128; ++i)
        s += (adj[(long)(seg * 128 + i) * Nn + n] > 0) ? 1.f : 0.f;
    sh[seg][t & 31] = s;
    __syncthreads();
    if (t < 32) {
        float v = 0.f;
#pragma unroll
        for (int k = 0; k < 8; ++k) v += sh[k][t];
        deg[blockIdx.x * 32 + t] = v;
    }
}

__global__ void k_cvtW(const float* __restrict__ W1, const float* __restrict__ W2,
                       u16* __restrict__ W1b, u16* __restrict__ W2b)
{
    int i = blockIdx.x * 256 + threadIdx.x;  // L*FF*F
    W1b[i] = f2b(W1[i]);
    W2b[i] = f2b(W2[i]);
}

// x[b][n][f] fp32 -> xh/xl[b][f][n] bf16 (hi/lo split)
__global__ __launch_bounds__(256) void k_xpose(const float* __restrict__ x,
                                               u16* __restrict__ xh, u16* __restrict__ xl)
{
    __shared__ float tile[64][132];
    const int b = blockIdx.y, n0 = blockIdx.x * 64, t = threadIdx.x;
#pragma unroll
    for (int i = 0; i < 8; ++i) {
        int s = i * 256 + t, nl = s >> 5, f4 = (s & 31) << 2;
        float4 v = *reinterpret_cast<const float4*>(&x[((long)b * Nn + n0 + nl) * F_ + f4]);
        tile[nl][f4] = v.x; tile[nl][f4 + 1] = v.y;
        tile[nl][f4 + 2] = v.z; tile[nl][f4 + 3] = v.w;
    }
    __syncthreads();
    const int f = t >> 1, nb = (t & 1) << 5;
    const long ob = ((long)b * F_ + f) * Nn + n0 + nb;
    union { u16 u[8]; float4 v; } Hv, Lv;
#pragma unroll
    for (int i = 0; i < 32; i += 8) {
#pragma unroll
        for (int j = 0; j < 8; ++j) {
            float v = tile[nb + i + j][f];
            bf16_t h = (bf16_t)v;
            Hv.u[j] = __builtin_bit_cast(u16, h);
            Lv.u[j] = f2b(v - (float)h);
        }
        *reinterpret_cast<float4*>(&xh[ob + i]) = Hv.v;
        *reinterpret_cast<float4*>(&xl[ob + i]) = Lv.v;
    }
}

// column partial sums: xsp[b][seg][f] = sum over 128 n-rows of x[b,n,f]
__global__ __launch_bounds__(256) void k_xs2(const float* __restrict__ x, float* __restrict__ xsp)
{
    __shared__ float sh[2][128];
    const int seg = blockIdx.x, b = blockIdx.y, t = threadIdx.x;
    const int f = t & 127, h2 = t >> 7;
    const float* p = x + ((long)b * Nn + seg * 128 + h2 * 64) * F_ + f;
    float s = 0.f;
    for (int i = 0; i < 64; ++i) s += p[(long)i * F_];
    sh[h2][f] = s;
    __syncthreads();
    if (t < 128) xsp[((long)b * 8 + seg) * 128 + t] = sh[0][t] + sh[1][t];
}

__global__ void k_hsum(const float* __restrict__ xsp, const float* __restrict__ Wl,
                       const float* __restrict__ bsl, float* __restrict__ hsum)
{
    int i = blockIdx.x * 256 + threadIdx.x;  // B*H*E
    int e = i & 127, h = (i >> 7) & 7, b = i >> 10;
    const float* w = Wl + ((long)h * E_ + e) * F_;
    const float* xp = xsp + (long)b * 8 * 128;
    float s = 0.f;
    for (int f = 0; f < F_; ++f) {
        float xv = 0.f;
#pragma unroll
        for (int sg = 0; sg < 8; ++sg) xv += xp[sg * 128 + f];
        s += xv * w[f];
    }
    hsum[i] = s + (float)Nn * bsl[h * E_ + e];
}

__global__ void k_d12(const float* __restrict__ Asl, const float* __restrict__ bsl,
                      float* __restrict__ d12)
{
    int i = blockIdx.x * 256 + threadIdx.x;  // 2*H*N
    int n = i & 1023, h = (i >> 10) & 7, w = i >> 13;
    const float* a = Asl + ((long)h * 2 * E_ + (long)w * E_) * Nn + n;
    const float* bb = bsl + h * E_;
    float s = 0.f;
    for (int e = 0; e < E_; ++e) s += bb[e] * a[(long)e * Nn];
    d12[((long)w * H_ + h) * Nn + n] = s;
}

// block per node n: stage Ct rows once, waves split batches
// Ct layout: [h][p][n][f], p=0 -> C1, p=1 -> C2
__global__ __launch_bounds__(256) void k_score2(
    const float* __restrict__ x, const float* __restrict__ y,
    const float* __restrict__ Ct,
    const float* __restrict__ d12, const float* __restrict__ deg,
    float* __restrict__ score)
{
    const int n = blockIdx.x, t = threadIdx.x;
    __shared__ float c1[H_][128], c2[H_][128];
#pragma unroll
    for (int i = 0; i < 4; ++i) {
        int s = i * 256 + t, h = s >> 7, f = s & 127;
        c1[h][f] = Ct[((long)(2 * h) * Nn + n) * F_ + f];
        c2[h][f] = Ct[((long)(2 * h + 1) * Nn + n) * F_ + f];
    }
    __syncthreads();
    const int w = t >> 6, l = t & 63;
    const float dg = deg[n];
    for (int bi = 0; bi < 8; ++bi) {
        const int b = w * 8 + bi;
        const long base = ((long)b * Nn + n) * F_;
        float x0 = x[base + l], x1 = x[base + l + 64];
        float y0 = y[base + l], y1 = y[base + l + 64];
#pragma unroll
        for (int h = 0; h < H_; ++h) {
            float p = x0 * c1[h][l] + x1 * c1[h][l + 64]
                    + y0 * c2[h][l] + y1 * c2[h][l + 64];
#pragma unroll
            for (int o = 32; o; o >>= 1) p += __shfl_xor(p, o);
            if (l == 0)
                score[((long)b * H_ + h) * Nn + n] =
                    p + d12[(long)h * Nn + n] + dg * d12[(long)(H_ + h) * Nn + n];
        }
    }
}

// att + residual + LN1 in place; also emits bf16 copy xb for FF1
__global__ __launch_bounds__(64) void k_attn_ln1(
    float* __restrict__ x, u16* __restrict__ xb, const float* __restrict__ score,
    const float* __restrict__ hsum, const float* __restrict__ g,
    const float* __restrict__ be)
{
    const int n = blockIdx.x, b = blockIdx.y, t = threadIdx.x;
    const long xbase = ((long)b * Nn + n) * F_;
    float v0 = x[xbase + t], v1 = x[xbase + t + 64];
    float a0 = 0.f, a1 = 0.f;
#pragma unroll
    for (int h = 0; h < H_; ++h) {
        float s = score[((long)b * H_ + h) * Nn + n];
        float h0 = hsum[((long)b * H_ + h) * E_ + t];
        float h1 = hsum[((long)b * H_ + h) * E_ + t + 64];
        float p0 = s * h0, p1 = s * h1;
        a0 += (p0 > 0.f ? p0 : 0.01f * p0);
        a1 += (p1 > 0.f ? p1 : 0.01f * p1);
    }
    v0 += a0; v1 += a1;
    float sum = v0 + v1;
#pragma unroll
    for (int o = 32; o; o >>= 1) sum += __shfl_xor(sum, o);
    const float mean = sum * (1.f / 128.f);
    const float d0 = v0 - mean, d1 = v1 - mean;
    float vs = d0 * d0 + d1 * d1;
#pragma unroll
    for (int o = 32; o; o >>= 1) vs += __shfl_xor(vs, o);
    const float rstd = rsqrtf(vs * (1.f / 128.f) + 1e-5f);
    float o0 = d0 * rstd * g[t] + be[t];
    float o1 = d1 * rstd * g[t + 64] + be[t + 64];
    x[xbase + t] = o0;       x[xbase + t + 64] = o1;
    xb[xbase + t] = f2b(o0); xb[xbase + t + 64] = f2b(o1);
}

__global__ __launch_bounds__(64) void k_ln2(
    float* __restrict__ x, const float* __restrict__ ffo,
    const float* __restrict__ g, const float* __restrict__ be)
{
    const int n = blockIdx.x, b = blockIdx.y, t = threadIdx.x;
    const long xbase = ((long)b * Nn + n) * F_;
    float v0 = x[xbase + t] + ffo[xbase + t];
    float v1 = x[xbase + t + 64] + ffo[xbase + t + 64];
    float sum = v0 + v1;
#pragma unroll
    for (int o = 32; o; o >>= 1) sum += __shfl_xor(sum, o);
    const float mean = sum * (1.f / 128.f);
    const float d0 = v0 - mean, d1 = v1 - mean;
    float vs = d0 * d0 + d1 * d1;
#pragma unroll
    for (int o = 32; o; o >>= 1) vs += __shfl_xor(vs, o);
    const float rstd = rsqrtf(vs * (1.f / 128.f) + 1e-5f);
    x[xbase + t]      = d0 * rstd * g[t] + be[t];
    x[xbase + t + 64] = d1 * rstd * g[t + 64] + be[t + 64];
}

__global__ __launch_bounds__(256) void k_final_partial(
    const float* __restrict__ x, const float* __restrict__ Wo,
    float* __restrict__ part)
{
    const int c = blockIdx.x;
    const int k0 = c * 256;
    __shared__ float xk[B_][256];
    __shared__ float woT[256][OUT_ + 1];
    const int t = threadIdx.x;
#pragma unroll
    for (int r = 0; r < 8; ++r) {
        int s = t + r * 256;
        int b = s >> 6, kq = (s & 63) << 2;
        float4 v = *reinterpret_cast<const float4*>(&x[(long)b * (Nn * F_) + k0 + kq]);
        v.x = fmaxf(v.x, 0.f); v.y = fmaxf(v.y, 0.f);
        v.z = fmaxf(v.z, 0.f); v.w = fmaxf(v.w, 0.f);
        *reinterpret_cast<float4*>(&xk[b][kq]) = v;
    }
#pragma unroll
    for (int r = 0; r < 16; ++r) {
        int s = t + r * 256;
        int o = s >> 6, kq = (s & 63) << 2;
        float4 v = *reinterpret_cast<const float4*>(&Wo[(long)o * (Nn * F_) + k0 + kq]);
        woT[kq + 0][o] = v.x; woT[kq + 1][o] = v.y;
        woT[kq + 2][o] = v.z; woT[kq + 3][o] = v.w;
    }
    __syncthreads();
    const int o = t & 63, bg = t >> 6;
    float acc[8] = {};
    for (int k = 0; k < 256; ++k) {
        float w = woT[k][o];
#pragma unroll
        for (int i = 0; i < 8; ++i) acc[i] += xk[bg * 8 + i][k] * w;
    }
#pragma unroll
    for (int i = 0; i < 8; ++i)
        part[((long)c * B_ + bg * 8 + i) * OUT_ + o] = acc[i];
}

__global__ void k_final_reduce(const float* __restrict__ part,
                               const float* __restrict__ bo, float* __restrict__ out)
{
    int i = blockIdx.x * 256 + threadIdx.x;
    int o = i & 63;
    float s = bo[o];
    for (int c = 0; c < 512; ++c) s += part[(long)c * (B_ * OUT_) + i];
    out[i] = s;
}

extern "C" void kernel_launch(void* const* d_in, const int* in_sizes, int n_in,
                              void* d_out, int out_size, void* d_ws, size_t ws_size,
                              hipStream_t stream)
{
    const float* x_in = (const float*)d_in[0];
    const int*   adj  = (const int*)d_in[1];
    const float* Ws   = (const float*)d_in[2];
    const float* bs   = (const float*)d_in[3];
    const float* As   = (const float*)d_in[4];
    const float* W1   = (const float*)d_in[5];
    const float* b1   = (const float*)d_in[6];
    const float* W2   = (const float*)d_in[7];
    const float* b2   = (const float*)d_in[8];
    const float* g1   = (const float*)d_in[9];
    const float* be1  = (const float*)d_in[10];
    const float* g2   = (const float*)d_in[11];
    const float* be2  = (const float*)d_in[12];
    const float* Wo   = (const float*)d_in[13];
    const float* bo   = (const float*)d_in[14];
    float* out = (float*)d_out;

    char* wsb = (char*)d_ws;
    u16*   maskTb = (u16*)wsb;                        // 2 MB
    float* xc     = (float*)(wsb + (2L << 20));       // 16 MB
    float* y      = (float*)(wsb + (18L << 20));      // 16 MB
    char*  R      = wsb + (34L << 20);                // 16 MB multi-use
    u16*   xTh    = (u16*)R;                          //  8 MB (phase A)
    u16*   xTl    = (u16*)(R + (8L << 20));           //  8 MB (phase A)
    float* score  = (float*)R;                        //  1 MB (after mask GEMM)
    u16*   Tb     = (u16*)R;                          // 16 MB (FF phase)
    float* part   = (float*)R;                        //  4 MB (final)
    float* Ct     = (float*)(wsb + (50L << 20));      //  8 MB [h][2][Nn][F]
    u16*   xb     = (u16*)Ct;                         //  8 MB alias (FF phase)
    char*  S      = wsb + (58L << 20);
    float* deg  = (float*)S;                          // 4 KB
    float* xsp  = (float*)(S + (4L << 10));           // 128 KB
    float* hsum = (float*)(S + (132L << 10));         // 128 KB
    float* d12  = (float*)(S + (260L << 10));         // 64 KB
    u16*   W1b  = (u16*)(S + (324L << 10));           // 512 KB
    u16*   W2b  = (u16*)(S + (836L << 10));           // 512 KB

    hipMemcpyAsync(xc, x_in, sizeof(float) * (long)B_ * Nn * F_,
                   hipMemcpyDeviceToDevice, stream);
    k_maskT<<<dim3(16, 16), 256, 0, stream>>>(adj, maskTb);
    k_degA<<<32, 256, 0, stream>>>(adj, deg);
    k_cvtW<<<(L_ * FF_ * F_) / 256, 256, 0, stream>>>(W1, W2, W1b, W2b);
    k_xpose<<<dim3(16, B_), 256, 0, stream>>>(xc, xTh, xTl);

    for (int l = 0; l < L_; ++l) {
        const float* Wl  = Ws + (long)l * H_ * E_ * F_;
        const float* bsl = bs + (long)l * H_ * E_;
        const float* Asl = As + (long)l * H_ * 2 * E_ * Nn;

        // Ct[h][p][n][f] = sum_e As[l,h,pE+e,n] * Ws[l,h,e,f]  (one merged launch)
        k_gemm_tn<<<dim3(16, 2, 16), 256, 0, stream>>>(
            Asl, Nn, (long)E_ * Nn, Wl, F_, (long)E_ * F_, 1,
            Ct, F_, (long)Nn * F_, E_);

        // y[b][n][f] = sum_j mask[j][n] x[b][j][f]  (bf16 MFMA, hi+lo exact split)
        // batch on grid-x: each XCD caches full mask + ~4 batches of xT in its L2
        k_mfma<128, true, 0, true><<<dim3(32, 1, 8), 256, 0, stream>>>(
            maskTb, Nn, 0L, xTh, xTl, Nn, (long)F_ * Nn,
            nullptr, y, nullptr, F_, (long)Nn * F_, Nn);

        k_xs2<<<dim3(8, B_), 256, 0, stream>>>(xc, xsp);
        k_hsum<<<(B_ * H_ * E_) / 256, 256, 0, stream>>>(xsp, Wl, bsl, hsum);
        k_d12<<<(2 * H_ * Nn) / 256, 256, 0, stream>>>(Asl, bsl, d12);
        k_score2<<<Nn, 256, 0, stream>>>(xc, y, Ct, d12, deg, score);
        k_attn_ln1<<<dim3(Nn, B_), 64, 0, stream>>>(xc, xb, score, hsum,
                                                    g1 + l * F_, be1 + l * F_);
        // FF: 2 chunks of 16384 rows; Tb (bf16) lives in R
        for (int c = 0; c < 2; ++c) {
            const long r0 = (long)c * 16384;
            k_mfma<128, false, 1><<<dim3(128, 4), 256, 0, stream>>>(
                xb + r0 * F_, F_, 0L, W1b + (long)l * FF_ * F_, nullptr, F_, 0L,
                b1 + l * FF_, nullptr, Tb, FF_, 0L, F_);
            k_mfma<64, false, 2><<<dim3(256, 1), 256, 0, stream>>>(
                Tb, FF_, 0L, W2b + (long)l * F_ * FF_, nullptr, FF_, 0L,
                b2 + l * F_, y + r0 * F_, nullptr, F_, 0L, FF_);
        }
        k_ln2<<<dim3(Nn, B_), 64, 0, stream>>>(xc, y, g2 + l * F_, be2 + l * F_);
        if (l < L_ - 1)
            k_xpose<<<dim3(16, B_), 256, 0, stream>>>(xc, xTh, xTl);
    }

    k_final_partial<<<512, 256, 0, stream>>>(xc, Wo, part);
    k_final_reduce<<<(B_ * OUT_) / 256, 256, 0, stream>>>(part, bo, out);
}

// Round 4
// 563.614 us; speedup vs baseline: 2.8870x; 1.2199x over previous
//
#include <hip/hip_runtime.h>

#define L_ 4
#define H_ 8
#define Nn 1024
#define F_ 128
#define E_ 128
#define FF_ 512
#define OUT_ 64
#define B_ 32
#define KTOT (Nn * F_)  // 131072

typedef unsigned short u16;
typedef __bf16 bf16_t;
typedef __attribute__((ext_vector_type(8))) __bf16 bf16x8;
typedef __attribute__((ext_vector_type(4))) float f32x4;

__device__ __forceinline__ u16 f2b(float v) {
    bf16_t h = (bf16_t)v;
    return __builtin_bit_cast(u16, h);
}

// ============ bf16 MFMA GEMM (NT): C[m,n] = sum_k A[m,k]*B[n,k] ============
// A,B bf16 row-major K-contiguous. BMx128 tile, BK=64, 256 thr.
// DUAL: second B operand (lo part) accumulated into same C.
// EPI: 0 plain fp32 out; 1 bias+relu -> bf16 out.
// GSWAP: batch on blockIdx.x (fastest) so each XCD gets few batches x all mtiles.
template <int BM, bool DUAL, int EPI, bool GSWAP = false>
__global__ __launch_bounds__(256) void k_mfma(
    const u16* __restrict__ A, int lda, long sAz,
    const u16* __restrict__ Bhp, const u16* __restrict__ Blp, int ldb, long sBz,
    const float* __restrict__ bias,
    float* __restrict__ Cf, u16* __restrict__ Cb, int ldc, long sCz, int K)
{
    constexpr int NF = (BM == 128) ? 4 : 2;
    constexpr int AIT = BM / 32;
    __shared__ __align__(16) u16 lds[BM * 64 + (DUAL ? 2 : 1) * 128 * 64];
    u16* Al = lds;
    u16* Bh = lds + BM * 64;
    u16* Bl = Bh + 128 * 64;
    const int t = threadIdx.x;
    const int w = t >> 6, l = t & 63, lr = l & 15, lg = l >> 4;
    const int wm0 = (BM == 128) ? (w >> 1) * 64 : 0;
    const int wn0 = (BM == 128) ? (w & 1) * 64 : w * 32;
    const int bidm = GSWAP ? blockIdx.z : blockIdx.x;
    const int bidz = GSWAP ? blockIdx.x : blockIdx.z;
    const int m0 = bidm * BM, n0 = blockIdx.y * 128;
    A += (long)bidz * sAz;
    Bhp += (long)bidz * sBz;
    if (DUAL) Blp += (long)bidz * sBz;

    f32x4 acc[4][NF] = {};

    for (int k0 = 0; k0 < K; k0 += 64) {
        __syncthreads();
#pragma unroll
        for (int i = 0; i < AIT; ++i) {
            int ch = i * 256 + t, row = ch >> 3, jq = ch & 7;
            *reinterpret_cast<float4*>(&Al[row * 64 + ((jq ^ (row & 7)) << 3)]) =
                *reinterpret_cast<const float4*>(&A[(long)(m0 + row) * lda + k0 + (jq << 3)]);
        }
#pragma unroll
        for (int i = 0; i < 4; ++i) {
            int ch = i * 256 + t, row = ch >> 3, jq = ch & 7;
            int dst = row * 64 + ((jq ^ (row & 7)) << 3);
            long src = (long)(n0 + row) * ldb + k0 + (jq << 3);
            *reinterpret_cast<float4*>(&Bh[dst]) = *reinterpret_cast<const float4*>(&Bhp[src]);
            if (DUAL)
                *reinterpret_cast<float4*>(&Bl[dst]) = *reinterpret_cast<const float4*>(&Blp[src]);
        }
        __syncthreads();
#pragma unroll
        for (int ks = 0; ks < 2; ++ks) {
            bf16x8 af[4], bh[NF], bl[NF];
            const int kq = ks * 4 + lg;
#pragma unroll
            for (int mf = 0; mf < 4; ++mf) {
                int row = wm0 + mf * 16 + lr;
                af[mf] = *reinterpret_cast<const bf16x8*>(&Al[row * 64 + ((kq ^ (row & 7)) << 3)]);
            }
#pragma unroll
            for (int nf = 0; nf < NF; ++nf) {
                int row = wn0 + nf * 16 + lr;
                int off = row * 64 + ((kq ^ (row & 7)) << 3);
                bh[nf] = *reinterpret_cast<const bf16x8*>(&Bh[off]);
                if (DUAL) bl[nf] = *reinterpret_cast<const bf16x8*>(&Bl[off]);
            }
#pragma unroll
            for (int mf = 0; mf < 4; ++mf)
#pragma unroll
                for (int nf = 0; nf < NF; ++nf) {
                    acc[mf][nf] = __builtin_amdgcn_mfma_f32_16x16x32_bf16(af[mf], bh[nf], acc[mf][nf], 0, 0, 0);
                    if (DUAL)
                        acc[mf][nf] = __builtin_amdgcn_mfma_f32_16x16x32_bf16(af[mf], bl[nf], acc[mf][nf], 0, 0, 0);
                }
        }
    }

    float bv[NF];
    if (EPI) {
#pragma unroll
        for (int nf = 0; nf < NF; ++nf) bv[nf] = bias[n0 + wn0 + nf * 16 + lr];
    }
    if (EPI == 1) Cb += (long)bidz * sCz;
    else          Cf += (long)bidz * sCz;
#pragma unroll
    for (int mf = 0; mf < 4; ++mf)
#pragma unroll
        for (int nf = 0; nf < NF; ++nf)
#pragma unroll
            for (int r = 0; r < 4; ++r) {
                long row = m0 + wm0 + mf * 16 + lg * 4 + r;
                int col = n0 + wn0 + nf * 16 + lr;
                float v = acc[mf][nf][r];
                if (EPI) v += bv[nf];
                if (EPI == 1) Cb[row * ldc + col] = f2b(fmaxf(v, 0.f));
                else          Cf[row * ldc + col] = v;
            }
}

// ============ FF2 + residual + LN2 fused. 64-row tile spans all F=128 cols ============
template <bool LAST>
__global__ __launch_bounds__(256) void k_ff2_ln2(
    const u16* __restrict__ Tb,   // [32768][512]
    const u16* __restrict__ W2b,  // [128][512]
    const float* __restrict__ b2,
    float* __restrict__ xc,       // [32768][128] in(residual)/out
    const float* __restrict__ g, const float* __restrict__ be,
    u16* __restrict__ xrb)        // LAST: relu(out) bf16
{
    __shared__ __align__(16) u16 Al[64 * 64];
    __shared__ __align__(16) u16 Bh[128 * 64];
    __shared__ float buf[64][132];
    const int t = threadIdx.x;
    const int w = t >> 6, l = t & 63, lr = l & 15, lg = l >> 4;
    const int wn0 = w * 32;
    const int m0 = blockIdx.x * 64;
    f32x4 acc[4][2] = {};

    for (int k0 = 0; k0 < FF_; k0 += 64) {
        __syncthreads();
#pragma unroll
        for (int i = 0; i < 2; ++i) {
            int ch = i * 256 + t, row = ch >> 3, jq = ch & 7;
            *reinterpret_cast<float4*>(&Al[row * 64 + ((jq ^ (row & 7)) << 3)]) =
                *reinterpret_cast<const float4*>(&Tb[(long)(m0 + row) * FF_ + k0 + (jq << 3)]);
        }
#pragma unroll
        for (int i = 0; i < 4; ++i) {
            int ch = i * 256 + t, row = ch >> 3, jq = ch & 7;
            *reinterpret_cast<float4*>(&Bh[row * 64 + ((jq ^ (row & 7)) << 3)]) =
                *reinterpret_cast<const float4*>(&W2b[(long)row * FF_ + k0 + (jq << 3)]);
        }
        __syncthreads();
#pragma unroll
        for (int ks = 0; ks < 2; ++ks) {
            const int kq = ks * 4 + lg;
            bf16x8 af[4], bf[2];
#pragma unroll
            for (int mf = 0; mf < 4; ++mf) {
                int row = mf * 16 + lr;
                af[mf] = *reinterpret_cast<const bf16x8*>(&Al[row * 64 + ((kq ^ (row & 7)) << 3)]);
            }
#pragma unroll
            for (int nf = 0; nf < 2; ++nf) {
                int row = wn0 + nf * 16 + lr;
                bf[nf] = *reinterpret_cast<const bf16x8*>(&Bh[row * 64 + ((kq ^ (row & 7)) << 3)]);
            }
#pragma unroll
            for (int mf = 0; mf < 4; ++mf)
#pragma unroll
                for (int nf = 0; nf < 2; ++nf)
                    acc[mf][nf] = __builtin_amdgcn_mfma_f32_16x16x32_bf16(af[mf], bf[nf], acc[mf][nf], 0, 0, 0);
        }
    }
    __syncthreads();
    // acc(+bias) -> buf
    float bv[2] = { b2[wn0 + lr], b2[wn0 + 16 + lr] };
#pragma unroll
    for (int mf = 0; mf < 4; ++mf)
#pragma unroll
        for (int nf = 0; nf < 2; ++nf)
#pragma unroll
            for (int r = 0; r < 4; ++r)
                buf[mf * 16 + lg * 4 + r][wn0 + nf * 16 + lr] = acc[mf][nf][r] + bv[nf];
    __syncthreads();
    const float gl0 = g[l], gl1 = g[l + 64], bl0 = be[l], bl1 = be[l + 64];
#pragma unroll
    for (int rr = 0; rr < 16; ++rr) {
        const int row = w * 16 + rr;
        const long xb_ = (long)(m0 + row) * F_;
        float v0 = buf[row][l] + xc[xb_ + l];
        float v1 = buf[row][l + 64] + xc[xb_ + l + 64];
        float sum = v0 + v1;
#pragma unroll
        for (int o = 32; o; o >>= 1) sum += __shfl_xor(sum, o);
        const float mean = sum * (1.f / 128.f);
        const float d0 = v0 - mean, d1 = v1 - mean;
        float vs = d0 * d0 + d1 * d1;
#pragma unroll
        for (int o = 32; o; o >>= 1) vs += __shfl_xor(vs, o);
        const float rstd = rsqrtf(vs * (1.f / 128.f) + 1e-5f);
        float o0 = d0 * rstd * gl0 + bl0;
        float o1 = d1 * rstd * gl1 + bl1;
        xc[xb_ + l] = o0;
        xc[xb_ + l + 64] = o1;
        if (LAST) {
            xrb[xb_ + l] = f2b(fmaxf(o0, 0.f));
            xrb[xb_ + l + 64] = f2b(fmaxf(o1, 0.f));
        }
    }
}

// ============ final projection: out[b,o] = relu(x).Wo^T, k-split MFMA ============
__global__ __launch_bounds__(256) void k_final_mfma(
    const u16* __restrict__ xrb,  // [32][131072]
    const u16* __restrict__ Wob,  // [64][131072]
    float* __restrict__ part)     // [256][32][64]
{
    __shared__ __align__(16) u16 Al[32 * 512];
    const int c = blockIdx.x;
    const long k0 = (long)c * 512;
    const int t = threadIdx.x, w = t >> 6, l = t & 63, lr = l & 15, lg = l >> 4;
#pragma unroll
    for (int i = 0; i < 8; ++i) {
        int ch = i * 256 + t, row = ch >> 6, jq = ch & 63;
        *reinterpret_cast<float4*>(&Al[row * 512 + ((jq ^ (row & 7)) << 3)]) =
            *reinterpret_cast<const float4*>(&xrb[(long)row * KTOT + k0 + (jq << 3)]);
    }
    __syncthreads();
    f32x4 acc[2] = {};
    const u16* Bp = Wob + (long)(w * 16 + lr) * KTOT + k0 + lg * 8;
#pragma unroll
    for (int ks = 0; ks < 16; ++ks) {
        bf16x8 bfr = *reinterpret_cast<const bf16x8*>(Bp + ks * 32);
        const int j8 = ks * 4 + lg;
#pragma unroll
        for (int mf = 0; mf < 2; ++mf) {
            int row = mf * 16 + lr;
            bf16x8 af = *reinterpret_cast<const bf16x8*>(&Al[row * 512 + ((j8 ^ (row & 7)) << 3)]);
            acc[mf] = __builtin_amdgcn_mfma_f32_16x16x32_bf16(af, bfr, acc[mf], 0, 0, 0);
        }
    }
#pragma unroll
    for (int mf = 0; mf < 2; ++mf)
#pragma unroll
        for (int r = 0; r < 4; ++r) {
            int b = mf * 16 + lg * 4 + r, o = w * 16 + lr;
            part[((long)c * B_ + b) * OUT_ + o] = acc[mf][r];
        }
}

__global__ void k_final_reduce(const float* __restrict__ part,
                               const float* __restrict__ bo, float* __restrict__ out)
{
    int i = blockIdx.x * 256 + threadIdx.x;  // B*OUT = 2048
    int o = i & 63;
    float s = bo[o];
    for (int c = 0; c < 256; ++c) s += part[(long)c * (B_ * OUT_) + i];
    out[i] = s;
}

// ---------------- fp32 GEMM TN: C[m,n]=sum_k A[k*lda+m]*B[k*ldb+n] ----------------
__global__ __launch_bounds__(256) void k_gemm_tn(
    const float* __restrict__ A, int lda, long sAz,
    const float* __restrict__ B, int ldb, long sBz, int bzshift,
    float* __restrict__ C, int ldc, long sCz, int K)
{
    A += (long)blockIdx.z * sAz;
    B += (long)(blockIdx.z >> bzshift) * sBz;
    C += (long)blockIdx.z * sCz;
    __shared__ float As[32][64];
    __shared__ float Bs[32][64];
    const int t = threadIdx.x;
    const int txn = t & 15, tym = t >> 4;
    const int m0 = blockIdx.x * 64, n0 = blockIdx.y * 64;
    float acc[4][4] = {};
    for (int k0 = 0; k0 < K; k0 += 32) {
#pragma unroll
        for (int r = 0; r < 2; ++r) {
            int s = t + r * 256;
            int kk = s >> 4, c4 = (s & 15) << 2;
            *reinterpret_cast<float4*>(&As[kk][c4]) =
                *reinterpret_cast<const float4*>(&A[(long)(k0 + kk) * lda + m0 + c4]);
            *reinterpret_cast<float4*>(&Bs[kk][c4]) =
                *reinterpret_cast<const float4*>(&B[(long)(k0 + kk) * ldb + n0 + c4]);
        }
        __syncthreads();
#pragma unroll
        for (int kk = 0; kk < 32; ++kk) {
            float4 a4 = *reinterpret_cast<const float4*>(&As[kk][tym << 2]);
            float4 b4 = *reinterpret_cast<const float4*>(&Bs[kk][txn << 2]);
            float av[4] = {a4.x, a4.y, a4.z, a4.w};
            float bv[4] = {b4.x, b4.y, b4.z, b4.w};
#pragma unroll
            for (int i = 0; i < 4; ++i)
#pragma unroll
                for (int j = 0; j < 4; ++j) acc[i][j] += av[i] * bv[j];
        }
        __syncthreads();
    }
#pragma unroll
    for (int i = 0; i < 4; ++i) {
        float4 v = make_float4(acc[i][0], acc[i][1], acc[i][2], acc[i][3]);
        *reinterpret_cast<float4*>(&C[(long)(m0 + (tym << 2) + i) * ldc + n0 + (txn << 2)]) = v;
    }
}

// ---------------- small kernels ----------------
__global__ __launch_bounds__(256) void k_maskT(const int* __restrict__ adj, u16* __restrict__ maskTb)
{
    __shared__ u16 tl[64][65];
    const int j0 = blockIdx.x * 64, n0 = blockIdx.y * 64, t = threadIdx.x;
#pragma unroll
    for (int i = 0; i < 16; ++i) {
        int s = i * 256 + t, jl = s >> 6, nl = s & 63;
        tl[jl][nl] = (adj[(long)(j0 + jl) * Nn + n0 + nl] > 0) ? 0x3F80 : 0;
    }
    __syncthreads();
#pragma unroll
    for (int i = 0; i < 16; ++i) {
        int s = i * 256 + t, nl = s >> 6, jl = s & 63;
        maskTb[(long)(n0 + nl) * Nn + j0 + jl] = tl[jl][nl];
    }
}

__global__ __launch_bounds__(256) void k_degA(const int* __restrict__ adj, float* __restrict__ deg)
{
    __shared__ float sh[8][32];
    const int t = threadIdx.x;
    const int n = blockIdx.x * 32 + (t & 31);
    const int seg = t >> 5;
    float s = 0.f;
    for (int i = 0; i < 128; ++i)
        s += (adj[(long)(seg * 128 + i) * Nn + n] > 0) ? 1.f : 0.f;
    sh[seg][t & 31] = s;
    __syncthreads();
    if (t < 32) {
        float v = 0.f;
#pragma unroll
        for (int k = 0; k < 8; ++k) v += sh[k][t];
        deg[blockIdx.x * 32 + t] = v;
    }
}

__global__ void k_cvtW(const float* __restrict__ W1, const float* __restrict__ W2,
                       u16* __restrict__ W1b, u16* __restrict__ W2b)
{
    int i = blockIdx.x * 256 + threadIdx.x;
    W1b[i] = f2b(W1[i]);
    W2b[i] = f2b(W2[i]);
}

__global__ void k_cvtWo(const float* __restrict__ Wo, u16* __restrict__ Wob)
{
    long i = ((long)blockIdx.x * 256 + threadIdx.x) * 8;
    float4 a = *reinterpret_cast<const float4*>(&Wo[i]);
    float4 b = *reinterpret_cast<const float4*>(&Wo[i + 4]);
    union { u16 u[8]; float4 v; } r;
    r.u[0] = f2b(a.x); r.u[1] = f2b(a.y); r.u[2] = f2b(a.z); r.u[3] = f2b(a.w);
    r.u[4] = f2b(b.x); r.u[5] = f2b(b.y); r.u[6] = f2b(b.z); r.u[7] = f2b(b.w);
    *reinterpret_cast<float4*>(&Wob[i]) = r.v;
}

// x[b][n][f] fp32 -> xh/xl[b][f][n] bf16 (hi/lo split)
__global__ __launch_bounds__(256) void k_xpose(const float* __restrict__ x,
                                               u16* __restrict__ xh, u16* __restrict__ xl)
{
    __shared__ float tile[64][132];
    const int b = blockIdx.y, n0 = blockIdx.x * 64, t = threadIdx.x;
#pragma unroll
    for (int i = 0; i < 8; ++i) {
        int s = i * 256 + t, nl = s >> 5, f4 = (s & 31) << 2;
        float4 v = *reinterpret_cast<const float4*>(&x[((long)b * Nn + n0 + nl) * F_ + f4]);
        tile[nl][f4] = v.x; tile[nl][f4 + 1] = v.y;
        tile[nl][f4 + 2] = v.z; tile[nl][f4 + 3] = v.w;
    }
    __syncthreads();
    const int f = t >> 1, nb = (t & 1) << 5;
    const long ob = ((long)b * F_ + f) * Nn + n0 + nb;
    union { u16 u[8]; float4 v; } Hv, Lv;
#pragma unroll
    for (int i = 0; i < 32; i += 8) {
#pragma unroll
        for (int j = 0; j < 8; ++j) {
            float v = tile[nb + i + j][f];
            bf16_t h = (bf16_t)v;
            Hv.u[j] = __builtin_bit_cast(u16, h);
            Lv.u[j] = f2b(v - (float)h);
        }
        *reinterpret_cast<float4*>(&xh[ob + i]) = Hv.v;
        *reinterpret_cast<float4*>(&xl[ob + i]) = Lv.v;
    }
}

__global__ __launch_bounds__(256) void k_xs2(const float* __restrict__ x, float* __restrict__ xsp)
{
    __shared__ float sh[2][128];
    const int seg = blockIdx.x, b = blockIdx.y, t = threadIdx.x;
    const int f = t & 127, h2 = t >> 7;
    const float* p = x + ((long)b * Nn + seg * 128 + h2 * 64) * F_ + f;
    float s = 0.f;
    for (int i = 0; i < 64; ++i) s += p[(long)i * F_];
    sh[h2][f] = s;
    __syncthreads();
    if (t < 128) xsp[((long)b * 8 + seg) * 128 + t] = sh[0][t] + sh[1][t];
}

__global__ void k_hsum(const float* __restrict__ xsp, const float* __restrict__ Wl,
                       const float* __restrict__ bsl, float* __restrict__ hsum)
{
    int i = blockIdx.x * 256 + threadIdx.x;
    int e = i & 127, h = (i >> 7) & 7, b = i >> 10;
    const float* w = Wl + ((long)h * E_ + e) * F_;
    const float* xp = xsp + (long)b * 8 * 128;
    float s = 0.f;
    for (int f = 0; f < F_; ++f) {
        float xv = 0.f;
#pragma unroll
        for (int sg = 0; sg < 8; ++sg) xv += xp[sg * 128 + f];
        s += xv * w[f];
    }
    hsum[i] = s + (float)Nn * bsl[h * E_ + e];
}

__global__ void k_d12(const float* __restrict__ Asl, const float* __restrict__ bsl,
                      float* __restrict__ d12)
{
    int i = blockIdx.x * 256 + threadIdx.x;
    int n = i & 1023, h = (i >> 10) & 7, w = i >> 13;
    const float* a = Asl + ((long)h * 2 * E_ + (long)w * E_) * Nn + n;
    const float* bb = bsl + h * E_;
    float s = 0.f;
    for (int e = 0; e < E_; ++e) s += bb[e] * a[(long)e * Nn];
    d12[((long)w * H_ + h) * Nn + n] = s;
}

// fused score + attention + residual + LN1. One block per node n, waves split batches.
__global__ __launch_bounds__(256) void k_score_ln1(
    float* __restrict__ x, const float* __restrict__ y,
    const float* __restrict__ Ct, const float* __restrict__ d12,
    const float* __restrict__ deg, const float* __restrict__ hsum,
    const float* __restrict__ g, const float* __restrict__ be,
    u16* __restrict__ xb)
{
    const int n = blockIdx.x, t = threadIdx.x;
    __shared__ float c1[H_][128], c2[H_][128];
    __shared__ float sbs[H_];
#pragma unroll
    for (int i = 0; i < 4; ++i) {
        int s = i * 256 + t, h = s >> 7, f = s & 127;
        c1[h][f] = Ct[((long)(2 * h) * Nn + n) * F_ + f];
        c2[h][f] = Ct[((long)(2 * h + 1) * Nn + n) * F_ + f];
    }
    if (t < H_) sbs[t] = d12[(long)t * Nn + n] + deg[n] * d12[(long)(H_ + t) * Nn + n];
    __syncthreads();
    const int w = t >> 6, l = t & 63;
    const float gl0 = g[l], gl1 = g[l + 64], bl0 = be[l], bl1 = be[l + 64];
    for (int bi = 0; bi < 8; ++bi) {
        const int b = w * 8 + bi;
        const long base = ((long)b * Nn + n) * F_;
        float x0 = x[base + l], x1 = x[base + l + 64];
        float y0 = y[base + l], y1 = y[base + l + 64];
        float a0 = 0.f, a1 = 0.f;
#pragma unroll
        for (int h = 0; h < H_; ++h) {
            float p = x0 * c1[h][l] + x1 * c1[h][l + 64]
                    + y0 * c2[h][l] + y1 * c2[h][l + 64];
#pragma unroll
            for (int o = 32; o; o >>= 1) p += __shfl_xor(p, o);
            float s = p + sbs[h];
            float h0 = hsum[((long)b * H_ + h) * E_ + l];
            float h1 = hsum[((long)b * H_ + h) * E_ + l + 64];
            float p0 = s * h0, p1 = s * h1;
            a0 += (p0 > 0.f ? p0 : 0.01f * p0);
            a1 += (p1 > 0.f ? p1 : 0.01f * p1);
        }
        float v0 = x0 + a0, v1 = x1 + a1;
        float sum = v0 + v1;
#pragma unroll
        for (int o = 32; o; o >>= 1) sum += __shfl_xor(sum, o);
        const float mean = sum * (1.f / 128.f);
        const float d0 = v0 - mean, d1 = v1 - mean;
        float vs = d0 * d0 + d1 * d1;
#pragma unroll
        for (int o = 32; o; o >>= 1) vs += __shfl_xor(vs, o);
        const float rstd = rsqrtf(vs * (1.f / 128.f) + 1e-5f);
        float o0 = d0 * rstd * gl0 + bl0;
        float o1 = d1 * rstd * gl1 + bl1;
        x[base + l] = o0;        x[base + l + 64] = o1;
        xb[base + l] = f2b(o0);  xb[base + l + 64] = f2b(o1);
    }
}

extern "C" void kernel_launch(void* const* d_in, const int* in_sizes, int n_in,
                              void* d_out, int out_size, void* d_ws, size_t ws_size,
                              hipStream_t stream)
{
    const float* x_in = (const float*)d_in[0];
    const int*   adj  = (const int*)d_in[1];
    const float* Ws   = (const float*)d_in[2];
    const float* bs   = (const float*)d_in[3];
    const float* As   = (const float*)d_in[4];
    const float* W1   = (const float*)d_in[5];
    const float* b1   = (const float*)d_in[6];
    const float* W2   = (const float*)d_in[7];
    const float* b2   = (const float*)d_in[8];
    const float* g1   = (const float*)d_in[9];
    const float* be1  = (const float*)d_in[10];
    const float* g2   = (const float*)d_in[11];
    const float* be2  = (const float*)d_in[12];
    const float* Wo   = (const float*)d_in[13];
    const float* bo   = (const float*)d_in[14];
    float* out = (float*)d_out;

    char* wsb = (char*)d_ws;
    u16*   maskTb = (u16*)wsb;                        //  0: 2 MB
    float* xc     = (float*)(wsb + (2L << 20));       //  2: 16 MB
    float* y      = (float*)(wsb + (18L << 20));      // 18: 16 MB
    char*  R      = wsb + (34L << 20);                // 34: 32 MB (union)
    u16*   xTh    = (u16*)R;                          //   8 MB (xpose->maskgemm)
    u16*   xTl    = (u16*)(R + (8L << 20));           //   8 MB
    u16*   Tb     = (u16*)R;                          //   32 MB (FF phase)
    float* Ct     = (float*)(wsb + (66L << 20));      // 66: 8 MB [2h+p][Nn][F]
    u16*   xb     = (u16*)(wsb + (74L << 20));        // 74: 8 MB
    u16*   xrb    = (u16*)(wsb + (82L << 20));        // 82: 8 MB
    u16*   Wob    = (u16*)(wsb + (90L << 20));        // 90: 16 MB
    float* part   = (float*)(wsb + (106L << 20));     // 106: 2 MB
    char*  S      = wsb + (108L << 20);
    float* deg  = (float*)S;                          // 4 KB
    float* xsp  = (float*)(S + (4L << 10));           // 128 KB
    float* hsum = (float*)(S + (132L << 10));         // 128 KB
    float* d12  = (float*)(S + (260L << 10));         // 64 KB
    u16*   W1b  = (u16*)(S + (324L << 10));           // 512 KB
    u16*   W2b  = (u16*)(S + (836L << 10));           // 512 KB

    hipMemcpyAsync(xc, x_in, sizeof(float) * (long)B_ * Nn * F_,
                   hipMemcpyDeviceToDevice, stream);
    k_maskT<<<dim3(16, 16), 256, 0, stream>>>(adj, maskTb);
    k_degA<<<32, 256, 0, stream>>>(adj, deg);
    k_cvtW<<<(L_ * FF_ * F_) / 256, 256, 0, stream>>>(W1, W2, W1b, W2b);
    k_cvtWo<<<(OUT_ * KTOT) / (256 * 8), 256, 0, stream>>>(Wo, Wob);
    k_xpose<<<dim3(16, B_), 256, 0, stream>>>(xc, xTh, xTl);

    for (int l = 0; l < L_; ++l) {
        const float* Wl  = Ws + (long)l * H_ * E_ * F_;
        const float* bsl = bs + (long)l * H_ * E_;
        const float* Asl = As + (long)l * H_ * 2 * E_ * Nn;

        // Ct[2h+p][n][f] = sum_e As[l,h,pE+e,n] * Ws[l,h,e,f]
        k_gemm_tn<<<dim3(16, 2, 16), 256, 0, stream>>>(
            Asl, Nn, (long)E_ * Nn, Wl, F_, (long)E_ * F_, 1,
            Ct, F_, (long)Nn * F_, E_);

        // y[b][n][f] = sum_j mask[j][n] x[b][j][f]  (bf16 MFMA, hi+lo exact split)
        k_mfma<128, true, 0, true><<<dim3(32, 1, 8), 256, 0, stream>>>(
            maskTb, Nn, 0L, xTh, xTl, Nn, (long)F_ * Nn,
            nullptr, y, nullptr, F_, (long)Nn * F_, Nn);

        k_xs2<<<dim3(8, B_), 256, 0, stream>>>(xc, xsp);
        k_hsum<<<(B_ * H_ * E_) / 256, 256, 0, stream>>>(xsp, Wl, bsl, hsum);
        k_d12<<<(2 * H_ * Nn) / 256, 256, 0, stream>>>(Asl, bsl, d12);
        k_score_ln1<<<Nn, 256, 0, stream>>>(xc, y, Ct, d12, deg, hsum,
                                            g1 + l * F_, be1 + l * F_, xb);
        // FF1 whole batch: Tb[32768][512] bf16 (relu+bias fused)
        k_mfma<128, false, 1><<<dim3(256, 4), 256, 0, stream>>>(
            xb, F_, 0L, W1b + (long)l * FF_ * F_, nullptr, F_, 0L,
            b1 + l * FF_, nullptr, Tb, FF_, 0L, F_);
        // FF2 + residual + LN2 fused (writes xc; last layer also xrb)
        if (l < L_ - 1) {
            k_ff2_ln2<false><<<512, 256, 0, stream>>>(
                Tb, W2b + (long)l * F_ * FF_, b2 + l * F_, xc,
                g2 + l * F_, be2 + l * F_, nullptr);
            k_xpose<<<dim3(16, B_), 256, 0, stream>>>(xc, xTh, xTl);
        } else {
            k_ff2_ln2<true><<<512, 256, 0, stream>>>(
                Tb, W2b + (long)l * F_ * FF_, b2 + l * F_, xc,
                g2 + l * F_, be2 + l * F_, xrb);
        }
    }

    k_final_mfma<<<256, 256, 0, stream>>>(xrb, Wob, part);
    k_final_reduce<<<(B_ * OUT_) / 256, 256, 0, stream>>>(part, bo, out);
}

// Round 5
// 494.655 us; speedup vs baseline: 3.2894x; 1.1394x over previous
//
#include <hip/hip_runtime.h>

#define L_ 4
#define H_ 8
#define Nn 1024
#define F_ 128
#define E_ 128
#define FF_ 512
#define OUT_ 64
#define B_ 32
#define KTOT (Nn * F_)  // 131072

typedef unsigned short u16;
typedef __bf16 bf16_t;
typedef __attribute__((ext_vector_type(8))) __bf16 bf16x8;
typedef __attribute__((ext_vector_type(4))) float f32x4;

__device__ __forceinline__ u16 f2b(float v) {
    bf16_t h = (bf16_t)v;
    return __builtin_bit_cast(u16, h);
}

// ---- async global->LDS, 16B per lane. Dest = wave-uniform base + lane*16B ----
typedef const __attribute__((address_space(1))) void* gvp;
typedef __attribute__((address_space(3))) void* lvp;
__device__ __forceinline__ void gll16(const void* g, void* l) {
    __builtin_amdgcn_global_load_lds((gvp)g, (lvp)l, 16, 0, 0);
}

// Stage R rows x 64 u16 (128B/row) tile to LDS, linear dest, XOR-swizzled SOURCE:
// LDS slot (row, s) ends up holding global chunk (row, s ^ (row&7)); reads use the
// same XOR -> bank-conflict-free ds_read_b128 (rule #21: both-sides-or-neither).
template <int R>
__device__ __forceinline__ void stage(const u16* __restrict__ g, int ldg,
                                      u16* lds, int w, int l) {
    const int r8 = l >> 3, jq = l & 7;
#pragma unroll
    for (int i = 0; i < R / 32; ++i) {
        const int row0 = w * (R / 4) + i * 8;
        const int row = row0 + r8;
        gll16(g + (long)row * ldg + ((jq ^ (row & 7)) << 3), lds + row0 * 64);
    }
}

// ============ bf16 MFMA GEMM (NT): C[m,n] = sum_k A[m,k]*B[n,k] ============
// BMxBN tile, BK=64, 256 thr (4 waves). DUAL: second B (lo part) into same C.
// EPI: 0 fp32 out; 1 bias+relu -> bf16 out.
// BSH=1: z=(2h+p): A += (z>>1)*sAz + (z&1)*128, B += (z>>1)*sBz  (Ct mode).
// GSWAP: batch on blockIdx.x (fastest) for XCD L2 locality.
template <int BM, int BN, bool DUAL, int EPI, int BSH, bool GSWAP>
__global__ __launch_bounds__(256) void k_mfma(
    const u16* __restrict__ A, int lda, long sAz,
    const u16* __restrict__ Bhp, const u16* __restrict__ Blp, int ldb, long sBz,
    const float* __restrict__ bias,
    float* __restrict__ Cf, u16* __restrict__ Cb, int ldc, long sCz, int K)
{
    constexpr int WN = (BN == 64) ? 1 : ((BM == 64) ? 4 : 2);
    constexpr int WM = 4 / WN;
    constexpr int SM = BM / WM, SN = BN / WN;
    constexpr int MF = SM / 16, NF = SN / 16;
    __shared__ __align__(16) u16 lds[BM * 64 + (DUAL ? 2 : 1) * BN * 64];
    u16* Al = lds;
    u16* Bh = lds + BM * 64;
    u16* Bl = Bh + BN * 64;
    const int t = threadIdx.x;
    const int w = t >> 6, l = t & 63, lr = l & 15, lg = l >> 4;
    const int wm0 = (w / WN) * SM, wn0 = (w % WN) * SN;
    const int bidm = GSWAP ? blockIdx.z : blockIdx.x;
    const int bidz = GSWAP ? blockIdx.x : blockIdx.z;
    const int m0 = bidm * BM, n0 = blockIdx.y * BN;
    A += BSH ? ((long)(bidz >> 1) * sAz + (long)(bidz & 1) * 128)
             : (long)bidz * sAz;
    Bhp += (long)(bidz >> BSH) * sBz;
    if (DUAL) Blp += (long)bidz * sBz;

    f32x4 acc[MF][NF] = {};

    for (int k0 = 0; k0 < K; k0 += 64) {
        __syncthreads();
        stage<BM>(A + (long)m0 * lda + k0, lda, Al, w, l);
        stage<BN>(Bhp + (long)n0 * ldb + k0, ldb, Bh, w, l);
        if (DUAL) stage<BN>(Blp + (long)n0 * ldb + k0, ldb, Bl, w, l);
        __syncthreads();
#pragma unroll
        for (int ks = 0; ks < 2; ++ks) {
            bf16x8 af[MF], bh[NF], bl[NF];
            const int kq = ks * 4 + lg;
#pragma unroll
            for (int mf = 0; mf < MF; ++mf) {
                int row = wm0 + mf * 16 + lr;
                af[mf] = *reinterpret_cast<const bf16x8*>(&Al[row * 64 + ((kq ^ (row & 7)) << 3)]);
            }
#pragma unroll
            for (int nf = 0; nf < NF; ++nf) {
                int row = wn0 + nf * 16 + lr;
                int off = row * 64 + ((kq ^ (row & 7)) << 3);
                bh[nf] = *reinterpret_cast<const bf16x8*>(&Bh[off]);
                if (DUAL) bl[nf] = *reinterpret_cast<const bf16x8*>(&Bl[off]);
            }
#pragma unroll
            for (int mf = 0; mf < MF; ++mf)
#pragma unroll
                for (int nf = 0; nf < NF; ++nf) {
                    acc[mf][nf] = __builtin_amdgcn_mfma_f32_16x16x32_bf16(af[mf], bh[nf], acc[mf][nf], 0, 0, 0);
                    if (DUAL)
                        acc[mf][nf] = __builtin_amdgcn_mfma_f32_16x16x32_bf16(af[mf], bl[nf], acc[mf][nf], 0, 0, 0);
                }
        }
    }

    float bv[NF];
    if (EPI) {
#pragma unroll
        for (int nf = 0; nf < NF; ++nf) bv[nf] = bias[n0 + wn0 + nf * 16 + lr];
    }
    if (EPI == 1) Cb += (long)bidz * sCz;
    else          Cf += (long)bidz * sCz;
#pragma unroll
    for (int mf = 0; mf < MF; ++mf)
#pragma unroll
        for (int nf = 0; nf < NF; ++nf)
#pragma unroll
            for (int r = 0; r < 4; ++r) {
                long row = m0 + wm0 + mf * 16 + lg * 4 + r;
                int col = n0 + wn0 + nf * 16 + lr;
                float v = acc[mf][nf][r];
                if (EPI) v += bv[nf];
                if (EPI == 1) Cb[row * ldc + col] = f2b(fmaxf(v, 0.f));
                else          Cf[row * ldc + col] = v;
            }
}

// ===== FF2 + residual + LN2 fused; non-LAST also emits transposed hi/lo bf16 =====
template <bool LAST>
__global__ __launch_bounds__(256) void k_ff2_ln2(
    const u16* __restrict__ Tb,   // [32768][512] bf16
    const u16* __restrict__ W2b,  // [128][512] bf16
    const float* __restrict__ b2,
    float* __restrict__ xc,       // [32768][128] residual in / out
    const float* __restrict__ g, const float* __restrict__ be,
    u16* __restrict__ xh, u16* __restrict__ xl,  // !LAST: [b][f][n] bf16 hi/lo
    u16* __restrict__ xrb)                       //  LAST: relu(out) bf16 row-major
{
    __shared__ __align__(16) char uu[64 * 133 * 4];   // union: staging | buf
    u16* Al = (u16*)uu;                                // 8 KB
    u16* Bh = (u16*)(uu + 64 * 64 * 2);                // 16 KB
    float (*buf)[133] = (float(*)[133])uu;             // 34 KB
    const int t = threadIdx.x;
    const int w = t >> 6, l = t & 63, lr = l & 15, lg = l >> 4;
    const int wn0 = w * 32;
    const int m0 = blockIdx.x * 64;
    f32x4 acc[4][2] = {};

    for (int k0 = 0; k0 < FF_; k0 += 64) {
        __syncthreads();
        stage<64>(Tb + (long)m0 * FF_ + k0, FF_, Al, w, l);
        stage<128>(W2b + k0, FF_, Bh, w, l);
        __syncthreads();
#pragma unroll
        for (int ks = 0; ks < 2; ++ks) {
            const int kq = ks * 4 + lg;
            bf16x8 af[4], bfr[2];
#pragma unroll
            for (int mf = 0; mf < 4; ++mf) {
                int row = mf * 16 + lr;
                af[mf] = *reinterpret_cast<const bf16x8*>(&Al[row * 64 + ((kq ^ (row & 7)) << 3)]);
            }
#pragma unroll
            for (int nf = 0; nf < 2; ++nf) {
                int row = wn0 + nf * 16 + lr;
                bfr[nf] = *reinterpret_cast<const bf16x8*>(&Bh[row * 64 + ((kq ^ (row & 7)) << 3)]);
            }
#pragma unroll
            for (int mf = 0; mf < 4; ++mf)
#pragma unroll
                for (int nf = 0; nf < 2; ++nf)
                    acc[mf][nf] = __builtin_amdgcn_mfma_f32_16x16x32_bf16(af[mf], bfr[nf], acc[mf][nf], 0, 0, 0);
        }
    }
    __syncthreads();   // staging LDS dead; reuse as buf
    float bv[2] = { b2[wn0 + lr], b2[wn0 + 16 + lr] };
#pragma unroll
    for (int mf = 0; mf < 4; ++mf)
#pragma unroll
        for (int nf = 0; nf < 2; ++nf)
#pragma unroll
            for (int r = 0; r < 4; ++r)
                buf[mf * 16 + lg * 4 + r][wn0 + nf * 16 + lr] = acc[mf][nf][r] + bv[nf];
    __syncthreads();
    const float gl0 = g[l], gl1 = g[l + 64], bl0 = be[l], bl1 = be[l + 64];
#pragma unroll
    for (int rr = 0; rr < 16; ++rr) {
        const int row = w * 16 + rr;
        const long xb_ = (long)(m0 + row) * F_;
        float v0 = buf[row][l] + xc[xb_ + l];
        float v1 = buf[row][l + 64] + xc[xb_ + l + 64];
        float sum = v0 + v1;
#pragma unroll
        for (int o = 32; o; o >>= 1) sum += __shfl_xor(sum, o);
        const float mean = sum * (1.f / 128.f);
        const float d0 = v0 - mean, d1 = v1 - mean;
        float vs = d0 * d0 + d1 * d1;
#pragma unroll
        for (int o = 32; o; o >>= 1) vs += __shfl_xor(vs, o);
        const float rstd = rsqrtf(vs * (1.f / 128.f) + 1e-5f);
        float o0 = d0 * rstd * gl0 + bl0;
        float o1 = d1 * rstd * gl1 + bl1;
        if (LAST) {
            xrb[xb_ + l] = f2b(fmaxf(o0, 0.f));
            xrb[xb_ + l + 64] = f2b(fmaxf(o1, 0.f));
        } else {
            xc[xb_ + l] = o0;       xc[xb_ + l + 64] = o1;
            buf[row][l] = o0;       buf[row][l + 64] = o1;
        }
    }
    if (!LAST) {   // transposed hi/lo write for next layer's mask GEMM
        __syncthreads();
        const int b = m0 >> 10, nb0 = m0 & 1023;
        const int n8 = (t & 7) * 8, fb = t >> 3;
#pragma unroll
        for (int i = 0; i < 4; ++i) {
            const int f = fb + 32 * i;
            union { u16 u[8]; float4 v; } Hv, Lv;
#pragma unroll
            for (int j = 0; j < 8; ++j) {
                float v = buf[n8 + j][f];
                bf16_t h = (bf16_t)v;
                Hv.u[j] = __builtin_bit_cast(u16, h);
                Lv.u[j] = f2b(v - (float)h);
            }
            const long ob = ((long)b * F_ + f) * Nn + nb0 + n8;
            *reinterpret_cast<float4*>(&xh[ob]) = Hv.v;
            *reinterpret_cast<float4*>(&xl[ob]) = Lv.v;
        }
    }
}

// ============ final projection: out[b,o] = relu(x).Wo^T, k-split MFMA ============
__global__ __launch_bounds__(256) void k_final_mfma(
    const u16* __restrict__ xrb,  // [32][131072]
    const u16* __restrict__ Wob,  // [64][131072]
    float* __restrict__ part)     // [256][32][64]
{
    __shared__ __align__(16) u16 Al[32 * 512];
    const int c = blockIdx.x;
    const long k0 = (long)c * 512;
    const int t = threadIdx.x, w = t >> 6, l = t & 63, lr = l & 15, lg = l >> 4;
#pragma unroll
    for (int i = 0; i < 8; ++i) {
        int ch = i * 256 + t, row = ch >> 6, jq = ch & 63;
        *reinterpret_cast<float4*>(&Al[row * 512 + ((jq ^ (row & 7)) << 3)]) =
            *reinterpret_cast<const float4*>(&xrb[(long)row * KTOT + k0 + (jq << 3)]);
    }
    __syncthreads();
    f32x4 acc[2] = {};
    const u16* Bp = Wob + (long)(w * 16 + lr) * KTOT + k0 + lg * 8;
#pragma unroll
    for (int ks = 0; ks < 16; ++ks) {
        bf16x8 bfr = *reinterpret_cast<const bf16x8*>(Bp + ks * 32);
        const int j8 = ks * 4 + lg;
#pragma unroll
        for (int mf = 0; mf < 2; ++mf) {
            int row = mf * 16 + lr;
            bf16x8 af = *reinterpret_cast<const bf16x8*>(&Al[row * 512 + ((j8 ^ (row & 7)) << 3)]);
            acc[mf] = __builtin_amdgcn_mfma_f32_16x16x32_bf16(af, bfr, acc[mf], 0, 0, 0);
        }
    }
#pragma unroll
    for (int mf = 0; mf < 2; ++mf)
#pragma unroll
        for (int r = 0; r < 4; ++r) {
            int b = mf * 16 + lg * 4 + r, o = w * 16 + lr;
            part[((long)c * B_ + b) * OUT_ + o] = acc[mf][r];
        }
}

__global__ void k_final_reduce(const float* __restrict__ part,
                               const float* __restrict__ bo, float* __restrict__ out)
{
    int i = blockIdx.x * 256 + threadIdx.x;  // B*OUT = 2048
    int o = i & 63;
    float s = bo[o];
    for (int c = 0; c < 256; ++c) s += part[(long)c * (B_ * OUT_) + i];
    out[i] = s;
}

// ---------------- small kernels ----------------
__global__ __launch_bounds__(256) void k_maskT(const int* __restrict__ adj, u16* __restrict__ maskTb)
{
    __shared__ u16 tl[64][65];
    const int j0 = blockIdx.x * 64, n0 = blockIdx.y * 64, t = threadIdx.x;
#pragma unroll
    for (int i = 0; i < 16; ++i) {
        int s = i * 256 + t, jl = s >> 6, nl = s & 63;
        tl[jl][nl] = (adj[(long)(j0 + jl) * Nn + n0 + nl] > 0) ? 0x3F80 : 0;
    }
    __syncthreads();
#pragma unroll
    for (int i = 0; i < 16; ++i) {
        int s = i * 256 + t, nl = s >> 6, jl = s & 63;
        maskTb[(long)(n0 + nl) * Nn + j0 + jl] = tl[jl][nl];
    }
}

// generic 64x64-tiled transpose fp32 -> bf16: out[z][c][r] = bf16(in[z][r][c])
__global__ __launch_bounds__(256) void k_tpb(const float* __restrict__ in,
                                             u16* __restrict__ out, int R, int C)
{
    __shared__ float tl[64][65];
    const int c0 = blockIdx.x * 64, r0 = blockIdx.y * 64, t = threadIdx.x;
    in  += (long)blockIdx.z * R * C;
    out += (long)blockIdx.z * R * C;
#pragma unroll
    for (int i = 0; i < 16; ++i) {
        int s = i * 256 + t, rl = s >> 6, cl = s & 63;
        tl[rl][cl] = in[(long)(r0 + rl) * C + c0 + cl];
    }
    __syncthreads();
#pragma unroll
    for (int i = 0; i < 16; ++i) {
        int s = i * 256 + t, cl = s >> 6, rl = s & 63;
        out[(long)(c0 + cl) * R + r0 + rl] = f2b(tl[rl][cl]);
    }
}

__global__ __launch_bounds__(256) void k_degA(const int* __restrict__ adj, float* __restrict__ deg)
{
    __shared__ float sh[8][32];
    const int t = threadIdx.x;
    const int n = blockIdx.x * 32 + (t & 31);
    const int seg = t >> 5;
    float s = 0.f;
    for (int i = 0; i < 128; ++i)
        s += (adj[(long)(seg * 128 + i) * Nn + n] > 0) ? 1.f : 0.f;
    sh[seg][t & 31] = s;
    __syncthreads();
    if (t < 32) {
        float v = 0.f;
#pragma unroll
        for (int k = 0; k < 8; ++k) v += sh[k][t];
        deg[blockIdx.x * 32 + t] = v;
    }
}

__global__ void k_cvtW(const float* __restrict__ W1, const float* __restrict__ W2,
                       u16* __restrict__ W1b, u16* __restrict__ W2b)
{
    int i = blockIdx.x * 256 + threadIdx.x;
    W1b[i] = f2b(W1[i]);
    W2b[i] = f2b(W2[i]);
}

__global__ void k_cvtWo(const float* __restrict__ Wo, u16* __restrict__ Wob)
{
    long i = ((long)blockIdx.x * 256 + threadIdx.x) * 8;
    float4 a = *reinterpret_cast<const float4*>(&Wo[i]);
    float4 b = *reinterpret_cast<const float4*>(&Wo[i + 4]);
    union { u16 u[8]; float4 v; } r;
    r.u[0] = f2b(a.x); r.u[1] = f2b(a.y); r.u[2] = f2b(a.z); r.u[3] = f2b(a.w);
    r.u[4] = f2b(b.x); r.u[5] = f2b(b.y); r.u[6] = f2b(b.z); r.u[7] = f2b(b.w);
    *reinterpret_cast<float4*>(&Wob[i]) = r.v;
}

// x[b][n][f] fp32 -> xh/xl[b][f][n] bf16 (hi/lo split) — prolog only
__global__ __launch_bounds__(256) void k_xpose(const float* __restrict__ x,
                                               u16* __restrict__ xh, u16* __restrict__ xl)
{
    __shared__ float tile[64][132];
    const int b = blockIdx.y, n0 = blockIdx.x * 64, t = threadIdx.x;
#pragma unroll
    for (int i = 0; i < 8; ++i) {
        int s = i * 256 + t, nl = s >> 5, f4 = (s & 31) << 2;
        float4 v = *reinterpret_cast<const float4*>(&x[((long)b * Nn + n0 + nl) * F_ + f4]);
        tile[nl][f4] = v.x; tile[nl][f4 + 1] = v.y;
        tile[nl][f4 + 2] = v.z; tile[nl][f4 + 3] = v.w;
    }
    __syncthreads();
    const int f = t >> 1, nb = (t & 1) << 5;
    const long ob = ((long)b * F_ + f) * Nn + n0 + nb;
    union { u16 u[8]; float4 v; } Hv, Lv;
#pragma unroll
    for (int i = 0; i < 32; i += 8) {
#pragma unroll
        for (int j = 0; j < 8; ++j) {
            float v = tile[nb + i + j][f];
            bf16_t h = (bf16_t)v;
            Hv.u[j] = __builtin_bit_cast(u16, h);
            Lv.u[j] = f2b(v - (float)h);
        }
        *reinterpret_cast<float4*>(&xh[ob + i]) = Hv.v;
        *reinterpret_cast<float4*>(&xl[ob + i]) = Lv.v;
    }
}

__global__ __launch_bounds__(256) void k_xs2(const float* __restrict__ x, float* __restrict__ xsp)
{
    __shared__ float sh[2][128];
    const int seg = blockIdx.x, b = blockIdx.y, t = threadIdx.x;
    const int f = t & 127, h2 = t >> 7;
    const float* p = x + ((long)b * Nn + seg * 128 + h2 * 64) * F_ + f;
    float s = 0.f;
    for (int i = 0; i < 64; ++i) s += p[(long)i * F_];
    sh[h2][f] = s;
    __syncthreads();
    if (t < 128) xsp[((long)b * 8 + seg) * 128 + t] = sh[0][t] + sh[1][t];
}

__global__ void k_hsum(const float* __restrict__ xsp, const float* __restrict__ Wl,
                       const float* __restrict__ bsl, float* __restrict__ hsum)
{
    int i = blockIdx.x * 256 + threadIdx.x;
    int e = i & 127, h = (i >> 7) & 7, b = i >> 10;
    const float* w = Wl + ((long)h * E_ + e) * F_;
    const float* xp = xsp + (long)b * 8 * 128;
    float s = 0.f;
    for (int f = 0; f < F_; ++f) {
        float xv = 0.f;
#pragma unroll
        for (int sg = 0; sg < 8; ++sg) xv += xp[sg * 128 + f];
        s += xv * w[f];
    }
    hsum[i] = s + (float)Nn * bsl[h * E_ + e];
}

__global__ void k_d12(const float* __restrict__ Asl, const float* __restrict__ bsl,
                      float* __restrict__ d12)
{
    int i = blockIdx.x * 256 + threadIdx.x;
    int n = i & 1023, h = (i >> 10) & 7, w = i >> 13;
    const float* a = Asl + ((long)h * 2 * E_ + (long)w * E_) * Nn + n;
    const float* bb = bsl + h * E_;
    float s = 0.f;
    for (int e = 0; e < E_; ++e) s += bb[e] * a[(long)e * Nn];
    d12[((long)w * H_ + h) * Nn + n] = s;
}

// fused score + attention + residual + LN1. One block per node n, waves split batches.
__global__ __launch_bounds__(256) void k_score_ln1(
    float* __restrict__ x, const float* __restrict__ y,
    const float* __restrict__ Ct, const float* __restrict__ d12,
    const float* __restrict__ deg, const float* __restrict__ hsum,
    const float* __restrict__ g, const float* __restrict__ be,
    u16* __restrict__ xb)
{
    const int n = blockIdx.x, t = threadIdx.x;
    __shared__ float c1[H_][128], c2[H_][128];
    __shared__ float sbs[H_];
#pragma unroll
    for (int i = 0; i < 4; ++i) {
        int s = i * 256 + t, h = s >> 7, f = s & 127;
        c1[h][f] = Ct[((long)(2 * h) * Nn + n) * F_ + f];
        c2[h][f] = Ct[((long)(2 * h + 1) * Nn + n) * F_ + f];
    }
    if (t < H_) sbs[t] = d12[(long)t * Nn + n] + deg[n] * d12[(long)(H_ + t) * Nn + n];
    __syncthreads();
    const int w = t >> 6, l = t & 63;
    const float gl0 = g[l], gl1 = g[l + 64], bl0 = be[l], bl1 = be[l + 64];
    for (int bi = 0; bi < 8; ++bi) {
        const int b = w * 8 + bi;
        const long base = ((long)b * Nn + n) * F_;
        float x0 = x[base + l], x1 = x[base + l + 64];
        float y0 = y[base + l], y1 = y[base + l + 64];
        float a0 = 0.f, a1 = 0.f;
#pragma unroll
        for (int h = 0; h < H_; ++h) {
            float p = x0 * c1[h][l] + x1 * c1[h][l + 64]
                    + y0 * c2[h][l] + y1 * c2[h][l + 64];
#pragma unroll
            for (int o = 32; o; o >>= 1) p += __shfl_xor(p, o);
            float s = p + sbs[h];
            float h0 = hsum[((long)b * H_ + h) * E_ + l];
            float h1 = hsum[((long)b * H_ + h) * E_ + l + 64];
            float p0 = s * h0, p1 = s * h1;
            a0 += (p0 > 0.f ? p0 : 0.01f * p0);
            a1 += (p1 > 0.f ? p1 : 0.01f * p1);
        }
        float v0 = x0 + a0, v1 = x1 + a1;
        float sum = v0 + v1;
#pragma unroll
        for (int o = 32; o; o >>= 1) sum += __shfl_xor(sum, o);
        const float mean = sum * (1.f / 128.f);
        const float d0 = v0 - mean, d1 = v1 - mean;
        float vs = d0 * d0 + d1 * d1;
#pragma unroll
        for (int o = 32; o; o >>= 1) vs += __shfl_xor(vs, o);
        const float rstd = rsqrtf(vs * (1.f / 128.f) + 1e-5f);
        float o0 = d0 * rstd * gl0 + bl0;
        float o1 = d1 * rstd * gl1 + bl1;
        x[base + l] = o0;        x[base + l + 64] = o1;
        xb[base + l] = f2b(o0);  xb[base + l + 64] = f2b(o1);
    }
}

extern "C" void kernel_launch(void* const* d_in, const int* in_sizes, int n_in,
                              void* d_out, int out_size, void* d_ws, size_t ws_size,
                              hipStream_t stream)
{
    const float* x_in = (const float*)d_in[0];
    const int*   adj  = (const int*)d_in[1];
    const float* Ws   = (const float*)d_in[2];
    const float* bs   = (const float*)d_in[3];
    const float* As   = (const float*)d_in[4];
    const float* W1   = (const float*)d_in[5];
    const float* b1   = (const float*)d_in[6];
    const float* W2   = (const float*)d_in[7];
    const float* b2   = (const float*)d_in[8];
    const float* g1   = (const float*)d_in[9];
    const float* be1  = (const float*)d_in[10];
    const float* g2   = (const float*)d_in[11];
    const float* be2  = (const float*)d_in[12];
    const float* Wo   = (const float*)d_in[13];
    const float* bo   = (const float*)d_in[14];
    float* out = (float*)d_out;

    char* wsb = (char*)d_ws;
    u16*   maskTb = (u16*)wsb;                        //   0: 2 MB
    float* xc     = (float*)(wsb + (2L << 20));       //   2: 16 MB
    float* y      = (float*)(wsb + (18L << 20));      //  18: 16 MB
    u16*   Tb     = (u16*)(wsb + (34L << 20));        //  34: 32 MB
    float* Ct     = (float*)(wsb + (66L << 20));      //  66: 8 MB [2h+p][Nn][F]
    u16*   xb     = (u16*)(wsb + (74L << 20));        //  74: 8 MB
    u16*   xrb    = (u16*)(wsb + (82L << 20));        //  82: 8 MB
    u16*   Wob    = (u16*)(wsb + (90L << 20));        //  90: 16 MB
    float* part   = (float*)(wsb + (106L << 20));     // 106: 2 MB
    u16*   xTh    = (u16*)(wsb + (108L << 20));       // 108: 8 MB
    u16*   xTl    = (u16*)(wsb + (116L << 20));       // 116: 8 MB
    u16*   AsTb   = (u16*)(wsb + (124L << 20));       // 124: 16 MB [LH][n][e2]
    u16*   WsTb   = (u16*)(wsb + (140L << 20));       // 140: 2 MB [LH][f][e]
    char*  S      = wsb + (143L << 20);
    float* deg  = (float*)S;                          // 4 KB
    float* xsp  = (float*)(S + (4L << 10));           // 128 KB
    float* hsum = (float*)(S + (132L << 10));         // 128 KB
    float* d12  = (float*)(S + (260L << 10));         // 64 KB
    u16*   W1b  = (u16*)(S + (324L << 10));           // 512 KB
    u16*   W2b  = (u16*)(S + (836L << 10));           // 512 KB

    hipMemcpyAsync(xc, x_in, sizeof(float) * (long)B_ * Nn * F_,
                   hipMemcpyDeviceToDevice, stream);
    k_maskT<<<dim3(16, 16), 256, 0, stream>>>(adj, maskTb);
    k_degA<<<32, 256, 0, stream>>>(adj, deg);
    k_cvtW<<<(L_ * FF_ * F_) / 256, 256, 0, stream>>>(W1, W2, W1b, W2b);
    k_cvtWo<<<(OUT_ * KTOT) / (256 * 8), 256, 0, stream>>>(Wo, Wob);
    k_tpb<<<dim3(16, 4, L_ * H_), 256, 0, stream>>>(As, AsTb, 2 * E_, Nn);
    k_tpb<<<dim3(2, 2, L_ * H_), 256, 0, stream>>>(Ws, WsTb, E_, F_);
    k_xpose<<<dim3(16, B_), 256, 0, stream>>>(xc, xTh, xTl);

    for (int l = 0; l < L_; ++l) {
        const float* Wl  = Ws + (long)l * H_ * E_ * F_;
        const float* bsl = bs + (long)l * H_ * E_;
        const float* Asl = As + (long)l * H_ * 2 * E_ * Nn;

        // Ct[2h+p][n][f] = sum_e AsT[n][p*128+e] * WsT[h][f][e]   (bf16 MFMA)
        k_mfma<64, 128, false, 0, 1, false><<<dim3(16, 1, 16), 256, 0, stream>>>(
            AsTb + (long)l * H_ * Nn * 2 * E_, 2 * E_, (long)Nn * 2 * E_,
            WsTb + (long)l * H_ * F_ * E_, nullptr, E_, (long)F_ * E_,
            nullptr, Ct, nullptr, F_, (long)Nn * F_, E_);

        // y[b][n][f] = sum_j mask[j][n] x[b][j][f]  (bf16 MFMA, hi+lo exact split)
        k_mfma<128, 64, true, 0, 0, true><<<dim3(32, 2, 8), 256, 0, stream>>>(
            maskTb, Nn, 0L, xTh, xTl, Nn, (long)F_ * Nn,
            nullptr, y, nullptr, F_, (long)Nn * F_, Nn);

        k_xs2<<<dim3(8, B_), 256, 0, stream>>>(xc, xsp);
        k_hsum<<<(B_ * H_ * E_) / 256, 256, 0, stream>>>(xsp, Wl, bsl, hsum);
        k_d12<<<(2 * H_ * Nn) / 256, 256, 0, stream>>>(Asl, bsl, d12);
        k_score_ln1<<<Nn, 256, 0, stream>>>(xc, y, Ct, d12, deg, hsum,
                                            g1 + l * F_, be1 + l * F_, xb);
        // FF1: Tb[32768][512] bf16 (bias+relu fused)
        k_mfma<128, 128, false, 1, 0, false><<<dim3(256, 4), 256, 0, stream>>>(
            xb, F_, 0L, W1b + (long)l * FF_ * F_, nullptr, F_, 0L,
            b1 + l * FF_, nullptr, Tb, FF_, 0L, F_);
        // FF2 + residual + LN2 (+ transposed hi/lo emit, or xrb on last layer)
        if (l < L_ - 1)
            k_ff2_ln2<false><<<512, 256, 0, stream>>>(
                Tb, W2b + (long)l * F_ * FF_, b2 + l * F_, xc,
                g2 + l * F_, be2 + l * F_, xTh, xTl, nullptr);
        else
            k_ff2_ln2<true><<<512, 256, 0, stream>>>(
                Tb, W2b + (long)l * F_ * FF_, b2 + l * F_, xc,
                g2 + l * F_, be2 + l * F_, nullptr, nullptr, xrb);
    }

    k_final_mfma<<<256, 256, 0, stream>>>(xrb, Wob, part);
    k_final_reduce<<<(B_ * OUT_) / 256, 256, 0, stream>>>(part, bo, out);
}

// Round 6
// 416.560 us; speedup vs baseline: 3.9061x; 1.1875x over previous
//
#include <hip/hip_runtime.h>

#define L_ 4
#define H_ 8
#define Nn 1024
#define F_ 128
#define E_ 128
#define FF_ 512
#define OUT_ 64
#define B_ 32
#define KTOT (Nn * F_)  // 131072

typedef unsigned short u16;
typedef __bf16 bf16_t;
typedef __attribute__((ext_vector_type(8))) __bf16 bf16x8;
typedef __attribute__((ext_vector_type(4))) float f32x4;

__device__ __forceinline__ u16 f2b(float v) {
    bf16_t h = (bf16_t)v;
    return __builtin_bit_cast(u16, h);
}

// ---- async global->LDS, 16B per lane. Dest = wave-uniform base + lane*16B ----
typedef const __attribute__((address_space(1))) void* gvp;
typedef __attribute__((address_space(3))) void* lvp;
__device__ __forceinline__ void gll16(const void* g, void* l) {
    __builtin_amdgcn_global_load_lds((gvp)g, (lvp)l, 16, 0, 0);
}

// Stage R rows x 64 u16 (128B/row) tile to LDS, linear dest, XOR-swizzled SOURCE.
template <int R>
__device__ __forceinline__ void stage(const u16* __restrict__ g, int ldg,
                                      u16* lds, int w, int l) {
    const int r8 = l >> 3, jq = l & 7;
#pragma unroll
    for (int i = 0; i < R / 32; ++i) {
        const int row0 = w * (R / 4) + i * 8;
        const int row = row0 + r8;
        gll16(g + (long)row * ldg + ((jq ^ (row & 7)) << 3), lds + row0 * 64);
    }
}

// ============ bf16 MFMA GEMM (NT): C[m,n] = sum_k A[m,k]*B[n,k] ============
// BMxBN tile, BK=64, 256 thr. DUAL: second B (lo) into same C. EPI: 0 fp32;
// 1 bias+relu->bf16. BSH=1: z addressing for (layer,head,part) Ct batch.
// GSWAP: batch on blockIdx.x. DBUF: 2-phase double-buffered staging.
template <int BM, int BN, bool DUAL, int EPI, int BSH, bool GSWAP, bool DBUF>
__global__ __launch_bounds__(256) void k_mfma(
    const u16* __restrict__ A, int lda, long sAz,
    const u16* __restrict__ Bhp, const u16* __restrict__ Blp, int ldb, long sBz,
    const float* __restrict__ bias,
    float* __restrict__ Cf, u16* __restrict__ Cb, int ldc, long sCz, int K)
{
    constexpr int WN = (BN == 64) ? 1 : ((BM == 64) ? 4 : 2);
    constexpr int WM = 4 / WN;
    constexpr int SM = BM / WM, SN = BN / WN;
    constexpr int MF = SM / 16, NF = SN / 16;
    constexpr int BUFE = BM * 64 + (DUAL ? 2 : 1) * BN * 64;
    __shared__ __align__(16) u16 lds[BUFE * (DBUF ? 2 : 1)];
    const int t = threadIdx.x;
    const int w = t >> 6, l = t & 63, lr = l & 15, lg = l >> 4;
    const int wm0 = (w / WN) * SM, wn0 = (w % WN) * SN;
    const int bidm = GSWAP ? blockIdx.z : blockIdx.x;
    const int bidz = GSWAP ? blockIdx.x : blockIdx.z;
    const int m0 = bidm * BM, n0 = blockIdx.y * BN;
    A += BSH ? ((long)(bidz >> 1) * sAz + (long)(bidz & 1) * 128)
             : (long)bidz * sAz;
    Bhp += (long)(bidz >> BSH) * sBz;
    if (DUAL) Blp += (long)bidz * sBz;

    f32x4 acc[MF][NF] = {};

    auto stageAll = [&](u16* base, int k0) {
        stage<BM>(A + (long)m0 * lda + k0, lda, base, w, l);
        stage<BN>(Bhp + (long)n0 * ldb + k0, ldb, base + BM * 64, w, l);
        if (DUAL) stage<BN>(Blp + (long)n0 * ldb + k0, ldb, base + BM * 64 + BN * 64, w, l);
    };
    auto compute = [&](const u16* base) {
        const u16* Al = base;
        const u16* Bh = base + BM * 64;
        const u16* Bl = Bh + BN * 64;
#pragma unroll
        for (int ks = 0; ks < 2; ++ks) {
            bf16x8 af[MF], bh[NF], bl[NF];
            const int kq = ks * 4 + lg;
#pragma unroll
            for (int mf = 0; mf < MF; ++mf) {
                int row = wm0 + mf * 16 + lr;
                af[mf] = *reinterpret_cast<const bf16x8*>(&Al[row * 64 + ((kq ^ (row & 7)) << 3)]);
            }
#pragma unroll
            for (int nf = 0; nf < NF; ++nf) {
                int row = wn0 + nf * 16 + lr;
                int off = row * 64 + ((kq ^ (row & 7)) << 3);
                bh[nf] = *reinterpret_cast<const bf16x8*>(&Bh[off]);
                if (DUAL) bl[nf] = *reinterpret_cast<const bf16x8*>(&Bl[off]);
            }
#pragma unroll
            for (int mf = 0; mf < MF; ++mf)
#pragma unroll
                for (int nf = 0; nf < NF; ++nf) {
                    acc[mf][nf] = __builtin_amdgcn_mfma_f32_16x16x32_bf16(af[mf], bh[nf], acc[mf][nf], 0, 0, 0);
                    if (DUAL)
                        acc[mf][nf] = __builtin_amdgcn_mfma_f32_16x16x32_bf16(af[mf], bl[nf], acc[mf][nf], 0, 0, 0);
                }
        }
    };

    if (DBUF) {
        stageAll(lds, 0);
        __syncthreads();
        int cur = 0;
        for (int k0 = 0; k0 < K; k0 += 64) {
            if (k0 + 64 < K) stageAll(lds + (cur ^ 1) * BUFE, k0 + 64);
            compute(lds + cur * BUFE);
            __syncthreads();
            cur ^= 1;
        }
    } else {
        for (int k0 = 0; k0 < K; k0 += 64) {
            __syncthreads();
            stageAll(lds, k0);
            __syncthreads();
            compute(lds);
        }
    }

    float bv[NF];
    if (EPI) {
#pragma unroll
        for (int nf = 0; nf < NF; ++nf) bv[nf] = bias[n0 + wn0 + nf * 16 + lr];
    }
    if (EPI == 1) Cb += (long)bidz * sCz;
    else          Cf += (long)bidz * sCz;
#pragma unroll
    for (int mf = 0; mf < MF; ++mf)
#pragma unroll
        for (int nf = 0; nf < NF; ++nf)
#pragma unroll
            for (int r = 0; r < 4; ++r) {
                long row = m0 + wm0 + mf * 16 + lg * 4 + r;
                int col = n0 + wn0 + nf * 16 + lr;
                float v = acc[mf][nf][r];
                if (EPI) v += bv[nf];
                if (EPI == 1) Cb[row * ldc + col] = f2b(fmaxf(v, 0.f));
                else          Cf[row * ldc + col] = v;
            }
}

// ===== FF2 + residual + LN2 fused (dbuf); non-LAST emits transposed hi/lo bf16
//       and per-block column partial sums xsp for next layer's hsum =====
template <bool LAST>
__global__ __launch_bounds__(256) void k_ff2_ln2(
    const u16* __restrict__ Tb,   // [32768][512] bf16
    const u16* __restrict__ W2b,  // [128][512] bf16
    const float* __restrict__ b2,
    float* __restrict__ xc,       // [32768][128] residual in / out
    const float* __restrict__ g, const float* __restrict__ be,
    u16* __restrict__ xh, u16* __restrict__ xl,  // !LAST: [b][f][n] bf16 hi/lo
    float* __restrict__ xsp,                     // !LAST: [b][16][128] partials
    u16* __restrict__ xrb)                       //  LAST: relu(out) bf16
{
    __shared__ __align__(16) char uu[49152];     // 2 x 24 KB staging | buf+ps
    const int t = threadIdx.x;
    const int w = t >> 6, l = t & 63, lr = l & 15, lg = l >> 4;
    const int wn0 = w * 32;
    const int m0 = blockIdx.x * 64;
    f32x4 acc[4][2] = {};

    auto stageAll = [&](char* base, int k0) {
        stage<64>(Tb + (long)m0 * FF_ + k0, FF_, (u16*)base, w, l);
        stage<128>(W2b + k0, FF_, (u16*)(base + 8192), w, l);
    };
    auto compute = [&](const char* base) {
        const u16* Al = (const u16*)base;
        const u16* Bh = (const u16*)(base + 8192);
#pragma unroll
        for (int ks = 0; ks < 2; ++ks) {
            const int kq = ks * 4 + lg;
            bf16x8 af[4], bfr[2];
#pragma unroll
            for (int mf = 0; mf < 4; ++mf) {
                int row = mf * 16 + lr;
                af[mf] = *reinterpret_cast<const bf16x8*>(&Al[row * 64 + ((kq ^ (row & 7)) << 3)]);
            }
#pragma unroll
            for (int nf = 0; nf < 2; ++nf) {
                int row = wn0 + nf * 16 + lr;
                bfr[nf] = *reinterpret_cast<const bf16x8*>(&Bh[row * 64 + ((kq ^ (row & 7)) << 3)]);
            }
#pragma unroll
            for (int mf = 0; mf < 4; ++mf)
#pragma unroll
                for (int nf = 0; nf < 2; ++nf)
                    acc[mf][nf] = __builtin_amdgcn_mfma_f32_16x16x32_bf16(af[mf], bfr[nf], acc[mf][nf], 0, 0, 0);
        }
    };

    stageAll(uu, 0);
    __syncthreads();
    int cur = 0;
    for (int k0 = 0; k0 < FF_; k0 += 64) {
        if (k0 + 64 < FF_) stageAll(uu + (cur ^ 1) * 24576, k0 + 64);
        compute(uu + cur * 24576);
        __syncthreads();
        cur ^= 1;
    }
    // staging LDS dead; reuse as buf / ps
    float (*buf)[133] = (float(*)[133])uu;
    float (*ps)[128]  = (float(*)[128])(uu + 36864);
    float bv[2] = { b2[wn0 + lr], b2[wn0 + 16 + lr] };
#pragma unroll
    for (int mf = 0; mf < 4; ++mf)
#pragma unroll
        for (int nf = 0; nf < 2; ++nf)
#pragma unroll
            for (int r = 0; r < 4; ++r)
                buf[mf * 16 + lg * 4 + r][wn0 + nf * 16 + lr] = acc[mf][nf][r] + bv[nf];
    __syncthreads();
    const float gl0 = g[l], gl1 = g[l + 64], bl0 = be[l], bl1 = be[l + 64];
    float s0 = 0.f, s1 = 0.f;
#pragma unroll
    for (int rr = 0; rr < 16; ++rr) {
        const int row = w * 16 + rr;
        const long xb_ = (long)(m0 + row) * F_;
        float v0 = buf[row][l] + xc[xb_ + l];
        float v1 = buf[row][l + 64] + xc[xb_ + l + 64];
        float sum = v0 + v1;
#pragma unroll
        for (int o = 32; o; o >>= 1) sum += __shfl_xor(sum, o);
        const float mean = sum * (1.f / 128.f);
        const float d0 = v0 - mean, d1 = v1 - mean;
        float vs = d0 * d0 + d1 * d1;
#pragma unroll
        for (int o = 32; o; o >>= 1) vs += __shfl_xor(vs, o);
        const float rstd = rsqrtf(vs * (1.f / 128.f) + 1e-5f);
        float o0 = d0 * rstd * gl0 + bl0;
        float o1 = d1 * rstd * gl1 + bl1;
        if (LAST) {
            xrb[xb_ + l] = f2b(fmaxf(o0, 0.f));
            xrb[xb_ + l + 64] = f2b(fmaxf(o1, 0.f));
        } else {
            xc[xb_ + l] = o0;       xc[xb_ + l + 64] = o1;
            buf[row][l] = o0;       buf[row][l + 64] = o1;
            s0 += o0;               s1 += o1;
        }
    }
    if (!LAST) {
        ps[w][l] = s0; ps[w][l + 64] = s1;
        __syncthreads();
        const int b = m0 >> 10, nb0 = m0 & 1023, seg = (m0 >> 6) & 15;
        const int n8 = (t & 7) * 8, fb = t >> 3;
#pragma unroll
        for (int i = 0; i < 4; ++i) {
            const int f = fb + 32 * i;
            union { u16 u[8]; float4 v; } Hv, Lv;
#pragma unroll
            for (int j = 0; j < 8; ++j) {
                float v = buf[n8 + j][f];
                bf16_t h = (bf16_t)v;
                Hv.u[j] = __builtin_bit_cast(u16, h);
                Lv.u[j] = f2b(v - (float)h);
            }
            const long ob = ((long)b * F_ + f) * Nn + nb0 + n8;
            *reinterpret_cast<float4*>(&xh[ob]) = Hv.v;
            *reinterpret_cast<float4*>(&xl[ob]) = Lv.v;
        }
        if (t < 128)
            xsp[((long)b * 16 + seg) * 128 + t] =
                ps[0][t] + ps[1][t] + ps[2][t] + ps[3][t];
    }
}

// ============ final projection: out[b,o] = relu(x).Wo^T, k-split MFMA ============
__global__ __launch_bounds__(256) void k_final_mfma(
    const u16* __restrict__ xrb, const u16* __restrict__ Wob,
    float* __restrict__ part)
{
    __shared__ __align__(16) u16 Al[32 * 512];
    const int c = blockIdx.x;
    const long k0 = (long)c * 512;
    const int t = threadIdx.x, w = t >> 6, l = t & 63, lr = l & 15, lg = l >> 4;
#pragma unroll
    for (int i = 0; i < 8; ++i) {
        int ch = i * 256 + t, row = ch >> 6, jq = ch & 63;
        *reinterpret_cast<float4*>(&Al[row * 512 + ((jq ^ (row & 7)) << 3)]) =
            *reinterpret_cast<const float4*>(&xrb[(long)row * KTOT + k0 + (jq << 3)]);
    }
    __syncthreads();
    f32x4 acc[2] = {};
    const u16* Bp = Wob + (long)(w * 16 + lr) * KTOT + k0 + lg * 8;
#pragma unroll
    for (int ks = 0; ks < 16; ++ks) {
        bf16x8 bfr = *reinterpret_cast<const bf16x8*>(Bp + ks * 32);
        const int j8 = ks * 4 + lg;
#pragma unroll
        for (int mf = 0; mf < 2; ++mf) {
            int row = mf * 16 + lr;
            bf16x8 af = *reinterpret_cast<const bf16x8*>(&Al[row * 512 + ((j8 ^ (row & 7)) << 3)]);
            acc[mf] = __builtin_amdgcn_mfma_f32_16x16x32_bf16(af, bfr, acc[mf], 0, 0, 0);
        }
    }
#pragma unroll
    for (int mf = 0; mf < 2; ++mf)
#pragma unroll
        for (int r = 0; r < 4; ++r) {
            int b = mf * 16 + lg * 4 + r, o = w * 16 + lr;
            part[((long)c * B_ + b) * OUT_ + o] = acc[mf][r];
        }
}

__global__ void k_final_reduce(const float* __restrict__ part,
                               const float* __restrict__ bo, float* __restrict__ out)
{
    int i = blockIdx.x * 256 + threadIdx.x;
    int o = i & 63;
    float s = bo[o];
    for (int c = 0; c < 256; ++c) s += part[(long)c * (B_ * OUT_) + i];
    out[i] = s;
}

// ---------------- small kernels ----------------
// maskTb[n][j] = bf16(adj[j][n] > 0); degi[n] += column count (int atomics)
__global__ __launch_bounds__(256) void k_maskT(const int* __restrict__ adj,
                                               u16* __restrict__ maskTb,
                                               int* __restrict__ degi)
{
    __shared__ u16 tl[64][65];
    const int j0 = blockIdx.x * 64, n0 = blockIdx.y * 64, t = threadIdx.x;
#pragma unroll
    for (int i = 0; i < 16; ++i) {
        int s = i * 256 + t, jl = s >> 6, nl = s & 63;
        tl[jl][nl] = (adj[(long)(j0 + jl) * Nn + n0 + nl] > 0) ? 0x3F80 : 0;
    }
    __syncthreads();
    if (t < 64) {
        int c = 0;
#pragma unroll
        for (int jl = 0; jl < 64; ++jl) c += (tl[jl][t] != 0);
        atomicAdd(&degi[n0 + t], c);
    }
#pragma unroll
    for (int i = 0; i < 16; ++i) {
        int s = i * 256 + t, nl = s >> 6, jl = s & 63;
        maskTb[(long)(n0 + nl) * Nn + j0 + jl] = tl[jl][nl];
    }
}

// generic 64x64-tiled transpose fp32 -> bf16
__global__ __launch_bounds__(256) void k_tpb(const float* __restrict__ in,
                                             u16* __restrict__ out, int R, int C)
{
    __shared__ float tl[64][65];
    const int c0 = blockIdx.x * 64, r0 = blockIdx.y * 64, t = threadIdx.x;
    in  += (long)blockIdx.z * R * C;
    out += (long)blockIdx.z * R * C;
#pragma unroll
    for (int i = 0; i < 16; ++i) {
        int s = i * 256 + t, rl = s >> 6, cl = s & 63;
        tl[rl][cl] = in[(long)(r0 + rl) * C + c0 + cl];
    }
    __syncthreads();
#pragma unroll
    for (int i = 0; i < 16; ++i) {
        int s = i * 256 + t, cl = s >> 6, rl = s & 63;
        out[(long)(c0 + cl) * R + r0 + rl] = f2b(tl[rl][cl]);
    }
}

__global__ void k_cvtW(const float* __restrict__ W1, const float* __restrict__ W2,
                       u16* __restrict__ W1b, u16* __restrict__ W2b)
{
    int i = blockIdx.x * 256 + threadIdx.x;
    W1b[i] = f2b(W1[i]);
    W2b[i] = f2b(W2[i]);
}

__global__ void k_cvtWo(const float* __restrict__ Wo, u16* __restrict__ Wob)
{
    long i = ((long)blockIdx.x * 256 + threadIdx.x) * 8;
    float4 a = *reinterpret_cast<const float4*>(&Wo[i]);
    float4 b = *reinterpret_cast<const float4*>(&Wo[i + 4]);
    union { u16 u[8]; float4 v; } r;
    r.u[0] = f2b(a.x); r.u[1] = f2b(a.y); r.u[2] = f2b(a.z); r.u[3] = f2b(a.w);
    r.u[4] = f2b(b.x); r.u[5] = f2b(b.y); r.u[6] = f2b(b.z); r.u[7] = f2b(b.w);
    *reinterpret_cast<float4*>(&Wob[i]) = r.v;
}

// x[b][n][f] fp32 -> xh/xl[b][f][n] bf16 (hi/lo split) — prolog only
__global__ __launch_bounds__(256) void k_xpose(const float* __restrict__ x,
                                               u16* __restrict__ xh, u16* __restrict__ xl)
{
    __shared__ float tile[64][132];
    const int b = blockIdx.y, n0 = blockIdx.x * 64, t = threadIdx.x;
#pragma unroll
    for (int i = 0; i < 8; ++i) {
        int s = i * 256 + t, nl = s >> 5, f4 = (s & 31) << 2;
        float4 v = *reinterpret_cast<const float4*>(&x[((long)b * Nn + n0 + nl) * F_ + f4]);
        tile[nl][f4] = v.x; tile[nl][f4 + 1] = v.y;
        tile[nl][f4 + 2] = v.z; tile[nl][f4 + 3] = v.w;
    }
    __syncthreads();
    const int f = t >> 1, nb = (t & 1) << 5;
    const long ob = ((long)b * F_ + f) * Nn + n0 + nb;
    union { u16 u[8]; float4 v; } Hv, Lv;
#pragma unroll
    for (int i = 0; i < 32; i += 8) {
#pragma unroll
        for (int j = 0; j < 8; ++j) {
            float v = tile[nb + i + j][f];
            bf16_t h = (bf16_t)v;
            Hv.u[j] = __builtin_bit_cast(u16, h);
            Lv.u[j] = f2b(v - (float)h);
        }
        *reinterpret_cast<float4*>(&xh[ob + i]) = Hv.v;
        *reinterpret_cast<float4*>(&xl[ob + i]) = Lv.v;
    }
}

// layer-0 column partials: xsp[b][seg16][f] = sum over 64 n-rows
__global__ __launch_bounds__(256) void k_xs2(const float* __restrict__ x, float* __restrict__ xsp)
{
    __shared__ float sh[2][128];
    const int seg = blockIdx.x, b = blockIdx.y, t = threadIdx.x;
    const int f = t & 127, h2 = t >> 7;
    const float* p = x + ((long)b * Nn + seg * 64 + h2 * 32) * F_ + f;
    float s = 0.f;
    for (int i = 0; i < 32; ++i) s += p[(long)i * F_];
    sh[h2][f] = s;
    __syncthreads();
    if (t < 128) xsp[((long)b * 16 + seg) * 128 + t] = sh[0][t] + sh[1][t];
}

__global__ void k_hsum(const float* __restrict__ xsp, const float* __restrict__ Wl,
                       const float* __restrict__ bsl, float* __restrict__ hsum)
{
    __shared__ float xs[128];
    const int i = blockIdx.x * 256 + threadIdx.x;  // B*H*E, block spans one b
    const int b = i >> 10;
    if (threadIdx.x < 128) {
        const float* xp = xsp + (long)b * 16 * 128 + threadIdx.x;
        float v = 0.f;
#pragma unroll
        for (int sg = 0; sg < 16; ++sg) v += xp[sg * 128];
        xs[threadIdx.x] = v;
    }
    __syncthreads();
    const int e = i & 127, h = (i >> 7) & 7;
    const float* w = Wl + ((long)h * E_ + e) * F_;
    float s = 0.f;
    for (int f = 0; f < F_; ++f) s += xs[f] * w[f];
    hsum[i] = s + (float)Nn * bsl[h * E_ + e];
}

// all-layer d12[l][w][h][n] = sum_e bs[l,h,e] * As[l,h,w*E+e,n]
__global__ void k_d12(const float* __restrict__ As, const float* __restrict__ bs,
                      float* __restrict__ d12all)
{
    const int lyr = blockIdx.y;
    const float* Asl = As + (long)lyr * H_ * 2 * E_ * Nn;
    const float* bsl = bs + (long)lyr * H_ * E_;
    int i = blockIdx.x * 256 + threadIdx.x;
    int n = i & 1023, h = (i >> 10) & 7, w = i >> 13;
    const float* a = Asl + ((long)h * 2 * E_ + (long)w * E_) * Nn + n;
    const float* bb = bsl + h * E_;
    float s = 0.f;
    for (int e = 0; e < E_; ++e) s += bb[e] * a[(long)e * Nn];
    d12all[(long)lyr * 2 * H_ * Nn + ((long)w * H_ + h) * Nn + n] = s;
}

// fused score + attention + residual + LN1
__global__ __launch_bounds__(256) void k_score_ln1(
    float* __restrict__ x, const float* __restrict__ y,
    const float* __restrict__ Ct, const float* __restrict__ d12,
    const int* __restrict__ degi, const float* __restrict__ hsum,
    const float* __restrict__ g, const float* __restrict__ be,
    u16* __restrict__ xb)
{
    const int n = blockIdx.x, t = threadIdx.x;
    __shared__ float c1[H_][128], c2[H_][128];
    __shared__ float sbs[H_];
#pragma unroll
    for (int i = 0; i < 4; ++i) {
        int s = i * 256 + t, h = s >> 7, f = s & 127;
        c1[h][f] = Ct[((long)(2 * h) * Nn + n) * F_ + f];
        c2[h][f] = Ct[((long)(2 * h + 1) * Nn + n) * F_ + f];
    }
    if (t < H_) sbs[t] = d12[(long)t * Nn + n] + (float)degi[n] * d12[(long)(H_ + t) * Nn + n];
    __syncthreads();
    const int w = t >> 6, l = t & 63;
    const float gl0 = g[l], gl1 = g[l + 64], bl0 = be[l], bl1 = be[l + 64];
    for (int bi = 0; bi < 8; ++bi) {
        const int b = w * 8 + bi;
        const long base = ((long)b * Nn + n) * F_;
        float x0 = x[base + l], x1 = x[base + l + 64];
        float y0 = y[base + l], y1 = y[base + l + 64];
        float a0 = 0.f, a1 = 0.f;
#pragma unroll
        for (int h = 0; h < H_; ++h) {
            float p = x0 * c1[h][l] + x1 * c1[h][l + 64]
                    + y0 * c2[h][l] + y1 * c2[h][l + 64];
#pragma unroll
            for (int o = 32; o; o >>= 1) p += __shfl_xor(p, o);
            float s = p + sbs[h];
            float h0 = hsum[((long)b * H_ + h) * E_ + l];
            float h1 = hsum[((long)b * H_ + h) * E_ + l + 64];
            float p0 = s * h0, p1 = s * h1;
            a0 += (p0 > 0.f ? p0 : 0.01f * p0);
            a1 += (p1 > 0.f ? p1 : 0.01f * p1);
        }
        float v0 = x0 + a0, v1 = x1 + a1;
        float sum = v0 + v1;
#pragma unroll
        for (int o = 32; o; o >>= 1) sum += __shfl_xor(sum, o);
        const float mean = sum * (1.f / 128.f);
        const float d0 = v0 - mean, d1 = v1 - mean;
        float vs = d0 * d0 + d1 * d1;
#pragma unroll
        for (int o = 32; o; o >>= 1) vs += __shfl_xor(vs, o);
        const float rstd = rsqrtf(vs * (1.f / 128.f) + 1e-5f);
        float o0 = d0 * rstd * gl0 + bl0;
        float o1 = d1 * rstd * gl1 + bl1;
        x[base + l] = o0;        x[base + l + 64] = o1;
        xb[base + l] = f2b(o0);  xb[base + l + 64] = f2b(o1);
    }
}

extern "C" void kernel_launch(void* const* d_in, const int* in_sizes, int n_in,
                              void* d_out, int out_size, void* d_ws, size_t ws_size,
                              hipStream_t stream)
{
    const float* x_in = (const float*)d_in[0];
    const int*   adj  = (const int*)d_in[1];
    const float* Ws   = (const float*)d_in[2];
    const float* bs   = (const float*)d_in[3];
    const float* As   = (const float*)d_in[4];
    const float* W1   = (const float*)d_in[5];
    const float* b1   = (const float*)d_in[6];
    const float* W2   = (const float*)d_in[7];
    const float* b2   = (const float*)d_in[8];
    const float* g1   = (const float*)d_in[9];
    const float* be1  = (const float*)d_in[10];
    const float* g2   = (const float*)d_in[11];
    const float* be2  = (const float*)d_in[12];
    const float* Wo   = (const float*)d_in[13];
    const float* bo   = (const float*)d_in[14];
    float* out = (float*)d_out;

    char* wsb = (char*)d_ws;
    u16*   maskTb = (u16*)wsb;                        //   0: 2 MB
    float* xc     = (float*)(wsb + (2L << 20));       //   2: 16 MB
    float* y      = (float*)(wsb + (18L << 20));      //  18: 16 MB
    u16*   Tb     = (u16*)(wsb + (34L << 20));        //  34: 32 MB
    float* CtAll  = (float*)(wsb + (66L << 20));      //  66: 32 MB [L][16][Nn][F]
    u16*   xb     = (u16*)(wsb + (98L << 20));        //  98: 8 MB
    u16*   xrb    = (u16*)(wsb + (106L << 20));       // 106: 8 MB
    u16*   Wob    = (u16*)(wsb + (114L << 20));       // 114: 16 MB
    float* part   = (float*)(wsb + (130L << 20));     // 130: 2 MB
    u16*   xTh    = (u16*)(wsb + (132L << 20));       // 132: 8 MB
    u16*   xTl    = (u16*)(wsb + (140L << 20));       // 140: 8 MB
    u16*   AsTb   = (u16*)(wsb + (148L << 20));       // 148: 16 MB [LH][n][e2]
    u16*   WsTb   = (u16*)(wsb + (164L << 20));       // 164: 2 MB [LH][f][e]
    char*  S      = wsb + (166L << 20);
    int*   degi   = (int*)S;                          // 4 KB
    float* xsp    = (float*)(S + (4L << 10));         // 256 KB [b][16][128]
    float* hsum   = (float*)(S + (260L << 10));       // 128 KB
    float* d12all = (float*)(S + (388L << 10));       // 256 KB
    u16*   W1b    = (u16*)(S + (644L << 10));         // 512 KB
    u16*   W2b    = (u16*)(S + (1156L << 10));        // 512 KB

    hipMemsetAsync(degi, 0, Nn * sizeof(int), stream);
    hipMemcpyAsync(xc, x_in, sizeof(float) * (long)B_ * Nn * F_,
                   hipMemcpyDeviceToDevice, stream);
    k_maskT<<<dim3(16, 16), 256, 0, stream>>>(adj, maskTb, degi);
    k_cvtW<<<(L_ * FF_ * F_) / 256, 256, 0, stream>>>(W1, W2, W1b, W2b);
    k_cvtWo<<<(OUT_ * KTOT) / (256 * 8), 256, 0, stream>>>(Wo, Wob);
    k_tpb<<<dim3(16, 4, L_ * H_), 256, 0, stream>>>(As, AsTb, 2 * E_, Nn);
    k_tpb<<<dim3(2, 2, L_ * H_), 256, 0, stream>>>(Ws, WsTb, E_, F_);
    k_xpose<<<dim3(16, B_), 256, 0, stream>>>(x_in, xTh, xTl);
    k_xs2<<<dim3(16, B_), 256, 0, stream>>>(x_in, xsp);
    k_d12<<<dim3((2 * H_ * Nn) / 256, L_), 256, 0, stream>>>(As, bs, d12all);
    // CtAll[l][2h+p][n][f] = sum_e AsT[l,h][n][p*128+e] * WsT[l,h][f][e]
    k_mfma<64, 128, false, 0, 1, false, false><<<dim3(16, 1, 64), 256, 0, stream>>>(
        AsTb, 2 * E_, (long)Nn * 2 * E_, WsTb, nullptr, E_, (long)F_ * E_,
        nullptr, CtAll, nullptr, F_, (long)Nn * F_, E_);

    for (int l = 0; l < L_; ++l) {
        const float* Wl  = Ws + (long)l * H_ * E_ * F_;
        const float* bsl = bs + (long)l * H_ * E_;

        // y[b][n][f] = sum_j mask[j][n] x[b][j][f]  (dbuf 2-phase, hi+lo)
        k_mfma<128, 64, true, 0, 0, true, true><<<dim3(32, 2, 8), 256, 0, stream>>>(
            maskTb, Nn, 0L, xTh, xTl, Nn, (long)F_ * Nn,
            nullptr, y, nullptr, F_, (long)Nn * F_, Nn);

        k_hsum<<<(B_ * H_ * E_) / 256, 256, 0, stream>>>(xsp, Wl, bsl, hsum);
        k_score_ln1<<<Nn, 256, 0, stream>>>(
            xc, y, CtAll + (long)l * 16 * Nn * F_, d12all + (long)l * 2 * H_ * Nn,
            degi, hsum, g1 + l * F_, be1 + l * F_, xb);
        // FF1: Tb[32768][512] bf16 (bias+relu fused)
        k_mfma<128, 128, false, 1, 0, false, false><<<dim3(256, 4), 256, 0, stream>>>(
            xb, F_, 0L, W1b + (long)l * FF_ * F_, nullptr, F_, 0L,
            b1 + l * FF_, nullptr, Tb, FF_, 0L, F_);
        // FF2 + residual + LN2 (+ transposed hi/lo + xsp partials, or xrb last)
        if (l < L_ - 1)
            k_ff2_ln2<false><<<512, 256, 0, stream>>>(
                Tb, W2b + (long)l * F_ * FF_, b2 + l * F_, xc,
                g2 + l * F_, be2 + l * F_, xTh, xTl, xsp, nullptr);
        else
            k_ff2_ln2<true><<<512, 256, 0, stream>>>(
                Tb, W2b + (long)l * F_ * FF_, b2 + l * F_, xc,
                g2 + l * F_, be2 + l * F_, nullptr, nullptr, nullptr, xrb);
    }

    k_final_mfma<<<256, 256, 0, stream>>>(xrb, Wob, part);
    k_final_reduce<<<(B_ * OUT_) / 256, 256, 0, stream>>>(part, bo, out);
}

// Round 7
// 394.193 us; speedup vs baseline: 4.1278x; 1.0567x over previous
//
#include <hip/hip_runtime.h>

#define L_ 4
#define H_ 8
#define Nn 1024
#define F_ 128
#define E_ 128
#define FF_ 512
#define OUT_ 64
#define B_ 32
#define KTOT (Nn * F_)  // 131072

typedef unsigned short u16;
typedef __bf16 bf16_t;
typedef __attribute__((ext_vector_type(8))) __bf16 bf16x8;
typedef __attribute__((ext_vector_type(4))) float f32x4;

__device__ __forceinline__ u16 f2b(float v) {
    bf16_t h = (bf16_t)v;
    return __builtin_bit_cast(u16, h);
}

// ---- async global->LDS, 16B per lane. Dest = wave-uniform base + lane*16B ----
typedef const __attribute__((address_space(1))) void* gvp;
typedef __attribute__((address_space(3))) void* lvp;
__device__ __forceinline__ void gll16(const void* g, void* l) {
    __builtin_amdgcn_global_load_lds((gvp)g, (lvp)l, 16, 0, 0);
}

// Stage R rows x 64 u16 (128B/row) tile to LDS, linear dest, XOR-swizzled SOURCE.
template <int R>
__device__ __forceinline__ void stage(const u16* __restrict__ g, int ldg,
                                      u16* lds, int w, int l) {
    const int r8 = l >> 3, jq = l & 7;
#pragma unroll
    for (int i = 0; i < R / 32; ++i) {
        const int row0 = w * (R / 4) + i * 8;
        const int row = row0 + r8;
        gll16(g + (long)row * ldg + ((jq ^ (row & 7)) << 3), lds + row0 * 64);
    }
}

// ============ bf16 MFMA GEMM (NT): C[m,n] = sum_k A[m,k]*B[n,k] ============
template <int BM, int BN, bool DUAL, int EPI, int BSH, bool GSWAP, bool DBUF>
__global__ __launch_bounds__(256) void k_mfma(
    const u16* __restrict__ A, int lda, long sAz,
    const u16* __restrict__ Bhp, const u16* __restrict__ Blp, int ldb, long sBz,
    const float* __restrict__ bias,
    float* __restrict__ Cf, u16* __restrict__ Cb, int ldc, long sCz, int K)
{
    constexpr int WN = (BN == 64) ? 1 : ((BM == 64) ? 4 : 2);
    constexpr int WM = 4 / WN;
    constexpr int SM = BM / WM, SN = BN / WN;
    constexpr int MF = SM / 16, NF = SN / 16;
    constexpr int BUFE = BM * 64 + (DUAL ? 2 : 1) * BN * 64;
    __shared__ __align__(16) u16 lds[BUFE * (DBUF ? 2 : 1)];
    const int t = threadIdx.x;
    const int w = t >> 6, l = t & 63, lr = l & 15, lg = l >> 4;
    const int wm0 = (w / WN) * SM, wn0 = (w % WN) * SN;
    const int bidm = GSWAP ? blockIdx.z : blockIdx.x;
    const int bidz = GSWAP ? blockIdx.x : blockIdx.z;
    const int m0 = bidm * BM, n0 = blockIdx.y * BN;
    A += BSH ? ((long)(bidz >> 1) * sAz + (long)(bidz & 1) * 128)
             : (long)bidz * sAz;
    Bhp += (long)(bidz >> BSH) * sBz;
    if (DUAL) Blp += (long)bidz * sBz;

    f32x4 acc[MF][NF] = {};

    auto stageAll = [&](u16* base, int k0) {
        stage<BM>(A + (long)m0 * lda + k0, lda, base, w, l);
        stage<BN>(Bhp + (long)n0 * ldb + k0, ldb, base + BM * 64, w, l);
        if (DUAL) stage<BN>(Blp + (long)n0 * ldb + k0, ldb, base + BM * 64 + BN * 64, w, l);
    };
    auto compute = [&](const u16* base) {
        const u16* Al = base;
        const u16* Bh = base + BM * 64;
        const u16* Bl = Bh + BN * 64;
#pragma unroll
        for (int ks = 0; ks < 2; ++ks) {
            bf16x8 af[MF], bh[NF], bl[NF];
            const int kq = ks * 4 + lg;
#pragma unroll
            for (int mf = 0; mf < MF; ++mf) {
                int row = wm0 + mf * 16 + lr;
                af[mf] = *reinterpret_cast<const bf16x8*>(&Al[row * 64 + ((kq ^ (row & 7)) << 3)]);
            }
#pragma unroll
            for (int nf = 0; nf < NF; ++nf) {
                int row = wn0 + nf * 16 + lr;
                int off = row * 64 + ((kq ^ (row & 7)) << 3);
                bh[nf] = *reinterpret_cast<const bf16x8*>(&Bh[off]);
                if (DUAL) bl[nf] = *reinterpret_cast<const bf16x8*>(&Bl[off]);
            }
#pragma unroll
            for (int mf = 0; mf < MF; ++mf)
#pragma unroll
                for (int nf = 0; nf < NF; ++nf) {
                    acc[mf][nf] = __builtin_amdgcn_mfma_f32_16x16x32_bf16(af[mf], bh[nf], acc[mf][nf], 0, 0, 0);
                    if (DUAL)
                        acc[mf][nf] = __builtin_amdgcn_mfma_f32_16x16x32_bf16(af[mf], bl[nf], acc[mf][nf], 0, 0, 0);
                }
        }
    };

    if (DBUF) {
        stageAll(lds, 0);
        __syncthreads();
        int cur = 0;
        for (int k0 = 0; k0 < K; k0 += 64) {
            if (k0 + 64 < K) stageAll(lds + (cur ^ 1) * BUFE, k0 + 64);
            compute(lds + cur * BUFE);
            __syncthreads();
            cur ^= 1;
        }
    } else {
        for (int k0 = 0; k0 < K; k0 += 64) {
            __syncthreads();
            stageAll(lds, k0);
            __syncthreads();
            compute(lds);
        }
    }

    float bv[NF];
    if (EPI) {
#pragma unroll
        for (int nf = 0; nf < NF; ++nf) bv[nf] = bias[n0 + wn0 + nf * 16 + lr];
    }
    if (EPI == 1) Cb += (long)bidz * sCz;
    else          Cf += (long)bidz * sCz;
#pragma unroll
    for (int mf = 0; mf < MF; ++mf)
#pragma unroll
        for (int nf = 0; nf < NF; ++nf)
#pragma unroll
            for (int r = 0; r < 4; ++r) {
                long row = m0 + wm0 + mf * 16 + lg * 4 + r;
                int col = n0 + wn0 + nf * 16 + lr;
                float v = acc[mf][nf][r];
                if (EPI) v += bv[nf];
                if (EPI == 1) Cb[row * ldc + col] = f2b(fmaxf(v, 0.f));
                else          Cf[row * ldc + col] = v;
            }
}

// ===== Fused FF1+FF2+residual+LN2. 64-row block, P never leaves the CU. =====
// LDS (u16 units): A halves [0,4096),[4096,8192); P halves [8192,12288),[12288,16384);
// W halves [16384,24576),[24576,32768). Epilogue overlays buf/ps on the same 64 KB.
template <bool LAST>
__global__ __launch_bounds__(256) void k_ff_ln2(
    const u16* __restrict__ xb,   // [32768][128] bf16 (LN1 out)
    const u16* __restrict__ W1b,  // [512][128] bf16
    const float* __restrict__ b1,
    const u16* __restrict__ W2b,  // [128][512] bf16
    const float* __restrict__ b2,
    float* __restrict__ xc,       // [32768][128] residual in / out
    const float* __restrict__ g, const float* __restrict__ be,
    u16* __restrict__ xh, u16* __restrict__ xl,  // !LAST: [b][f][n] bf16 hi/lo
    float* __restrict__ xsp,                     // !LAST: [b][16][128] partials
    u16* __restrict__ xrb)                       //  LAST: relu(out) bf16
{
    __shared__ __align__(16) u16 lds[32768];     // 64 KB
    const int t = threadIdx.x;
    const int w = t >> 6, l = t & 63, lr = l & 15, lg = l >> 4;
    const int wn0 = w * 32;
    const int m0 = blockIdx.x * 64;
    u16* A0 = lds;
    u16* P0 = lds + 8192;
    u16* W0 = lds + 16384;

    // stage A (both k-halves) once
    stage<64>(xb + (long)m0 * F_,      F_, A0, w, l);
    stage<64>(xb + (long)m0 * F_ + 64, F_, A0 + 4096, w, l);

    f32x4 acc2[4][2] = {};
    for (int c = 0; c < 4; ++c) {
        __syncthreads();   // W region free (prev FF2 done); 1st iter: pairs with stage drain below
        stage<128>(W1b + (long)(c * 128) * F_,      F_, W0, w, l);
        stage<128>(W1b + (long)(c * 128) * F_ + 64, F_, W0 + 8192, w, l);
        __syncthreads();   // A + W1 ready
        f32x4 acc1[4][2] = {};
#pragma unroll
        for (int kh = 0; kh < 2; ++kh) {
            const u16* Ah = A0 + kh * 4096;
            const u16* Wh = W0 + kh * 8192;
#pragma unroll
            for (int ks = 0; ks < 2; ++ks) {
                const int kq = ks * 4 + lg;
                bf16x8 af[4], bfr[2];
#pragma unroll
                for (int mf = 0; mf < 4; ++mf) {
                    int row = mf * 16 + lr;
                    af[mf] = *reinterpret_cast<const bf16x8*>(&Ah[row * 64 + ((kq ^ (row & 7)) << 3)]);
                }
#pragma unroll
                for (int nf = 0; nf < 2; ++nf) {
                    int row = wn0 + nf * 16 + lr;
                    bfr[nf] = *reinterpret_cast<const bf16x8*>(&Wh[row * 64 + ((kq ^ (row & 7)) << 3)]);
                }
#pragma unroll
                for (int mf = 0; mf < 4; ++mf)
#pragma unroll
                    for (int nf = 0; nf < 2; ++nf)
                        acc1[mf][nf] = __builtin_amdgcn_mfma_f32_16x16x32_bf16(af[mf], bfr[nf], acc1[mf][nf], 0, 0, 0);
            }
        }
        // bias + relu -> P (swizzled bf16, same layout convention as staged tiles)
        float b1v[2] = { b1[c * 128 + wn0 + lr], b1[c * 128 + wn0 + 16 + lr] };
#pragma unroll
        for (int mf = 0; mf < 4; ++mf)
#pragma unroll
            for (int nf = 0; nf < 2; ++nf)
#pragma unroll
                for (int r = 0; r < 4; ++r) {
                    int row = mf * 16 + lg * 4 + r;
                    int cc = wn0 + nf * 16 + lr;
                    int c6 = cc & 63;
                    float v = fmaxf(acc1[mf][nf][r] + b1v[nf], 0.f);
                    P0[(cc >> 6) * 4096 + row * 64 + ((((c6 >> 3) ^ (row & 7))) << 3) + (c6 & 7)] = f2b(v);
                }
        __syncthreads();   // P visible; W1 reads done
        stage<128>(W2b + c * 128,      FF_, W0, w, l);
        stage<128>(W2b + c * 128 + 64, FF_, W0 + 8192, w, l);
        __syncthreads();   // W2 ready
#pragma unroll
        for (int kh = 0; kh < 2; ++kh) {
            const u16* Ph = P0 + kh * 4096;
            const u16* Wh = W0 + kh * 8192;
#pragma unroll
            for (int ks = 0; ks < 2; ++ks) {
                const int kq = ks * 4 + lg;
                bf16x8 af[4], bfr[2];
#pragma unroll
                for (int mf = 0; mf < 4; ++mf) {
                    int row = mf * 16 + lr;
                    af[mf] = *reinterpret_cast<const bf16x8*>(&Ph[row * 64 + ((kq ^ (row & 7)) << 3)]);
                }
#pragma unroll
                for (int nf = 0; nf < 2; ++nf) {
                    int row = wn0 + nf * 16 + lr;
                    bfr[nf] = *reinterpret_cast<const bf16x8*>(&Wh[row * 64 + ((kq ^ (row & 7)) << 3)]);
                }
#pragma unroll
                for (int mf = 0; mf < 4; ++mf)
#pragma unroll
                    for (int nf = 0; nf < 2; ++nf)
                        acc2[mf][nf] = __builtin_amdgcn_mfma_f32_16x16x32_bf16(af[mf], bfr[nf], acc2[mf][nf], 0, 0, 0);
            }
        }
    }
    __syncthreads();   // staging LDS dead; overlay buf / ps
    float (*buf)[132] = (float(*)[132])lds;                 // 33792 B
    float (*ps)[128]  = (float(*)[128])((char*)lds + 34816);
    float bv[2] = { b2[wn0 + lr], b2[wn0 + 16 + lr] };
#pragma unroll
    for (int mf = 0; mf < 4; ++mf)
#pragma unroll
        for (int nf = 0; nf < 2; ++nf)
#pragma unroll
            for (int r = 0; r < 4; ++r)
                buf[mf * 16 + lg * 4 + r][wn0 + nf * 16 + lr] = acc2[mf][nf][r] + bv[nf];
    __syncthreads();
    const float gl0 = g[l], gl1 = g[l + 64], bl0 = be[l], bl1 = be[l + 64];
    float s0 = 0.f, s1 = 0.f;
#pragma unroll
    for (int rr = 0; rr < 16; ++rr) {
        const int row = w * 16 + rr;
        const long xb_ = (long)(m0 + row) * F_;
        float v0 = buf[row][l] + xc[xb_ + l];
        float v1 = buf[row][l + 64] + xc[xb_ + l + 64];
        float sum = v0 + v1;
#pragma unroll
        for (int o = 32; o; o >>= 1) sum += __shfl_xor(sum, o);
        const float mean = sum * (1.f / 128.f);
        const float d0 = v0 - mean, d1 = v1 - mean;
        float vs = d0 * d0 + d1 * d1;
#pragma unroll
        for (int o = 32; o; o >>= 1) vs += __shfl_xor(vs, o);
        const float rstd = rsqrtf(vs * (1.f / 128.f) + 1e-5f);
        float o0 = d0 * rstd * gl0 + bl0;
        float o1 = d1 * rstd * gl1 + bl1;
        if (LAST) {
            xrb[xb_ + l] = f2b(fmaxf(o0, 0.f));
            xrb[xb_ + l + 64] = f2b(fmaxf(o1, 0.f));
        } else {
            xc[xb_ + l] = o0;       xc[xb_ + l + 64] = o1;
            buf[row][l] = o0;       buf[row][l + 64] = o1;
            s0 += o0;               s1 += o1;
        }
    }
    if (!LAST) {
        ps[w][l] = s0; ps[w][l + 64] = s1;
        __syncthreads();
        const int b = m0 >> 10, nb0 = m0 & 1023, seg = (m0 >> 6) & 15;
        const int n8 = (t & 7) * 8, fb = t >> 3;
#pragma unroll
        for (int i = 0; i < 4; ++i) {
            const int f = fb + 32 * i;
            union { u16 u[8]; float4 v; } Hv, Lv;
#pragma unroll
            for (int j = 0; j < 8; ++j) {
                float v = buf[n8 + j][f];
                bf16_t h = (bf16_t)v;
                Hv.u[j] = __builtin_bit_cast(u16, h);
                Lv.u[j] = f2b(v - (float)h);
            }
            const long ob = ((long)b * F_ + f) * Nn + nb0 + n8;
            *reinterpret_cast<float4*>(&xh[ob]) = Hv.v;
            *reinterpret_cast<float4*>(&xl[ob]) = Lv.v;
        }
        if (t < 128)
            xsp[((long)b * 16 + seg) * 128 + t] =
                ps[0][t] + ps[1][t] + ps[2][t] + ps[3][t];
    }
}

// ============ final projection: out[b,o] = relu(x).Wo^T, k-split MFMA ============
__global__ __launch_bounds__(256) void k_final_mfma(
    const u16* __restrict__ xrb, const u16* __restrict__ Wob,
    float* __restrict__ part)
{
    __shared__ __align__(16) u16 Al[32 * 512];
    const int c = blockIdx.x;
    const long k0 = (long)c * 512;
    const int t = threadIdx.x, w = t >> 6, l = t & 63, lr = l & 15, lg = l >> 4;
#pragma unroll
    for (int i = 0; i < 8; ++i) {
        int ch = i * 256 + t, row = ch >> 6, jq = ch & 63;
        *reinterpret_cast<float4*>(&Al[row * 512 + ((jq ^ (row & 7)) << 3)]) =
            *reinterpret_cast<const float4*>(&xrb[(long)row * KTOT + k0 + (jq << 3)]);
    }
    __syncthreads();
    f32x4 acc[2] = {};
    const u16* Bp = Wob + (long)(w * 16 + lr) * KTOT + k0 + lg * 8;
#pragma unroll
    for (int ks = 0; ks < 16; ++ks) {
        bf16x8 bfr = *reinterpret_cast<const bf16x8*>(Bp + ks * 32);
        const int j8 = ks * 4 + lg;
#pragma unroll
        for (int mf = 0; mf < 2; ++mf) {
            int row = mf * 16 + lr;
            bf16x8 af = *reinterpret_cast<const bf16x8*>(&Al[row * 512 + ((j8 ^ (row & 7)) << 3)]);
            acc[mf] = __builtin_amdgcn_mfma_f32_16x16x32_bf16(af, bfr, acc[mf], 0, 0, 0);
        }
    }
#pragma unroll
    for (int mf = 0; mf < 2; ++mf)
#pragma unroll
        for (int r = 0; r < 4; ++r) {
            int b = mf * 16 + lg * 4 + r, o = w * 16 + lr;
            part[((long)c * B_ + b) * OUT_ + o] = acc[mf][r];
        }
}

__global__ void k_final_reduce(const float* __restrict__ part,
                               const float* __restrict__ bo, float* __restrict__ out)
{
    int i = blockIdx.x * 256 + threadIdx.x;
    int o = i & 63;
    float s = bo[o];
    for (int c = 0; c < 256; ++c) s += part[(long)c * (B_ * OUT_) + i];
    out[i] = s;
}

// ---------------- small kernels ----------------
__global__ __launch_bounds__(256) void k_maskT(const int* __restrict__ adj,
                                               u16* __restrict__ maskTb,
                                               int* __restrict__ degi)
{
    __shared__ u16 tl[64][65];
    const int j0 = blockIdx.x * 64, n0 = blockIdx.y * 64, t = threadIdx.x;
#pragma unroll
    for (int i = 0; i < 16; ++i) {
        int s = i * 256 + t, jl = s >> 6, nl = s & 63;
        tl[jl][nl] = (adj[(long)(j0 + jl) * Nn + n0 + nl] > 0) ? 0x3F80 : 0;
    }
    __syncthreads();
    if (t < 64) {
        int c = 0;
#pragma unroll
        for (int jl = 0; jl < 64; ++jl) c += (tl[jl][t] != 0);
        atomicAdd(&degi[n0 + t], c);
    }
#pragma unroll
    for (int i = 0; i < 16; ++i) {
        int s = i * 256 + t, nl = s >> 6, jl = s & 63;
        maskTb[(long)(n0 + nl) * Nn + j0 + jl] = tl[jl][nl];
    }
}

__global__ __launch_bounds__(256) void k_tpb(const float* __restrict__ in,
                                             u16* __restrict__ out, int R, int C)
{
    __shared__ float tl[64][65];
    const int c0 = blockIdx.x * 64, r0 = blockIdx.y * 64, t = threadIdx.x;
    in  += (long)blockIdx.z * R * C;
    out += (long)blockIdx.z * R * C;
#pragma unroll
    for (int i = 0; i < 16; ++i) {
        int s = i * 256 + t, rl = s >> 6, cl = s & 63;
        tl[rl][cl] = in[(long)(r0 + rl) * C + c0 + cl];
    }
    __syncthreads();
#pragma unroll
    for (int i = 0; i < 16; ++i) {
        int s = i * 256 + t, cl = s >> 6, rl = s & 63;
        out[(long)(c0 + cl) * R + r0 + rl] = f2b(tl[rl][cl]);
    }
}

__global__ void k_cvtW(const float* __restrict__ W1, const float* __restrict__ W2,
                       u16* __restrict__ W1b, u16* __restrict__ W2b)
{
    int i = blockIdx.x * 256 + threadIdx.x;
    W1b[i] = f2b(W1[i]);
    W2b[i] = f2b(W2[i]);
}

__global__ void k_cvtWo(const float* __restrict__ Wo, u16* __restrict__ Wob)
{
    long i = ((long)blockIdx.x * 256 + threadIdx.x) * 8;
    float4 a = *reinterpret_cast<const float4*>(&Wo[i]);
    float4 b = *reinterpret_cast<const float4*>(&Wo[i + 4]);
    union { u16 u[8]; float4 v; } r;
    r.u[0] = f2b(a.x); r.u[1] = f2b(a.y); r.u[2] = f2b(a.z); r.u[3] = f2b(a.w);
    r.u[4] = f2b(b.x); r.u[5] = f2b(b.y); r.u[6] = f2b(b.z); r.u[7] = f2b(b.w);
    *reinterpret_cast<float4*>(&Wob[i]) = r.v;
}

__global__ __launch_bounds__(256) void k_xpose(const float* __restrict__ x,
                                               u16* __restrict__ xh, u16* __restrict__ xl)
{
    __shared__ float tile[64][132];
    const int b = blockIdx.y, n0 = blockIdx.x * 64, t = threadIdx.x;
#pragma unroll
    for (int i = 0; i < 8; ++i) {
        int s = i * 256 + t, nl = s >> 5, f4 = (s & 31) << 2;
        float4 v = *reinterpret_cast<const float4*>(&x[((long)b * Nn + n0 + nl) * F_ + f4]);
        tile[nl][f4] = v.x; tile[nl][f4 + 1] = v.y;
        tile[nl][f4 + 2] = v.z; tile[nl][f4 + 3] = v.w;
    }
    __syncthreads();
    const int f = t >> 1, nb = (t & 1) << 5;
    const long ob = ((long)b * F_ + f) * Nn + n0 + nb;
    union { u16 u[8]; float4 v; } Hv, Lv;
#pragma unroll
    for (int i = 0; i < 32; i += 8) {
#pragma unroll
        for (int j = 0; j < 8; ++j) {
            float v = tile[nb + i + j][f];
            bf16_t h = (bf16_t)v;
            Hv.u[j] = __builtin_bit_cast(u16, h);
            Lv.u[j] = f2b(v - (float)h);
        }
        *reinterpret_cast<float4*>(&xh[ob + i]) = Hv.v;
        *reinterpret_cast<float4*>(&xl[ob + i]) = Lv.v;
    }
}

__global__ __launch_bounds__(256) void k_xs2(const float* __restrict__ x, float* __restrict__ xsp)
{
    __shared__ float sh[2][128];
    const int seg = blockIdx.x, b = blockIdx.y, t = threadIdx.x;
    const int f = t & 127, h2 = t >> 7;
    const float* p = x + ((long)b * Nn + seg * 64 + h2 * 32) * F_ + f;
    float s = 0.f;
    for (int i = 0; i < 32; ++i) s += p[(long)i * F_];
    sh[h2][f] = s;
    __syncthreads();
    if (t < 128) xsp[((long)b * 16 + seg) * 128 + t] = sh[0][t] + sh[1][t];
}

__global__ void k_hsum(const float* __restrict__ xsp, const float* __restrict__ Wl,
                       const float* __restrict__ bsl, float* __restrict__ hsum)
{
    __shared__ float xs[128];
    const int i = blockIdx.x * 256 + threadIdx.x;
    const int b = i >> 10;
    if (threadIdx.x < 128) {
        const float* xp = xsp + (long)b * 16 * 128 + threadIdx.x;
        float v = 0.f;
#pragma unroll
        for (int sg = 0; sg < 16; ++sg) v += xp[sg * 128];
        xs[threadIdx.x] = v;
    }
    __syncthreads();
    const int e = i & 127, h = (i >> 7) & 7;
    const float* w = Wl + ((long)h * E_ + e) * F_;
    float s = 0.f;
    for (int f = 0; f < F_; ++f) s += xs[f] * w[f];
    hsum[i] = s + (float)Nn * bsl[h * E_ + e];
}

__global__ void k_d12(const float* __restrict__ As, const float* __restrict__ bs,
                      float* __restrict__ d12all)
{
    const int lyr = blockIdx.y;
    const float* Asl = As + (long)lyr * H_ * 2 * E_ * Nn;
    const float* bsl = bs + (long)lyr * H_ * E_;
    int i = blockIdx.x * 256 + threadIdx.x;
    int n = i & 1023, h = (i >> 10) & 7, w = i >> 13;
    const float* a = Asl + ((long)h * 2 * E_ + (long)w * E_) * Nn + n;
    const float* bb = bsl + h * E_;
    float s = 0.f;
    for (int e = 0; e < E_; ++e) s += bb[e] * a[(long)e * Nn];
    d12all[(long)lyr * 2 * H_ * Nn + ((long)w * H_ + h) * Nn + n] = s;
}

__global__ __launch_bounds__(256) void k_score_ln1(
    float* __restrict__ x, const float* __restrict__ y,
    const float* __restrict__ Ct, const float* __restrict__ d12,
    const int* __restrict__ degi, const float* __restrict__ hsum,
    const float* __restrict__ g, const float* __restrict__ be,
    u16* __restrict__ xb)
{
    const int n = blockIdx.x, t = threadIdx.x;
    __shared__ float c1[H_][128], c2[H_][128];
    __shared__ float sbs[H_];
#pragma unroll
    for (int i = 0; i < 4; ++i) {
        int s = i * 256 + t, h = s >> 7, f = s & 127;
        c1[h][f] = Ct[((long)(2 * h) * Nn + n) * F_ + f];
        c2[h][f] = Ct[((long)(2 * h + 1) * Nn + n) * F_ + f];
    }
    if (t < H_) sbs[t] = d12[(long)t * Nn + n] + (float)degi[n] * d12[(long)(H_ + t) * Nn + n];
    __syncthreads();
    const int w = t >> 6, l = t & 63;
    const float gl0 = g[l], gl1 = g[l + 64], bl0 = be[l], bl1 = be[l + 64];
    for (int bi = 0; bi < 8; ++bi) {
        const int b = w * 8 + bi;
        const long base = ((long)b * Nn + n) * F_;
        float x0 = x[base + l], x1 = x[base + l + 64];
        float y0 = y[base + l], y1 = y[base + l + 64];
        float a0 = 0.f, a1 = 0.f;
#pragma unroll
        for (int h = 0; h < H_; ++h) {
            float p = x0 * c1[h][l] + x1 * c1[h][l + 64]
                    + y0 * c2[h][l] + y1 * c2[h][l + 64];
#pragma unroll
            for (int o = 32; o; o >>= 1) p += __shfl_xor(p, o);
            float s = p + sbs[h];
            float h0 = hsum[((long)b * H_ + h) * E_ + l];
            float h1 = hsum[((long)b * H_ + h) * E_ + l + 64];
            float p0 = s * h0, p1 = s * h1;
            a0 += (p0 > 0.f ? p0 : 0.01f * p0);
            a1 += (p1 > 0.f ? p1 : 0.01f * p1);
        }
        float v0 = x0 + a0, v1 = x1 + a1;
        float sum = v0 + v1;
#pragma unroll
        for (int o = 32; o; o >>= 1) sum += __shfl_xor(sum, o);
        const float mean = sum * (1.f / 128.f);
        const float d0 = v0 - mean, d1 = v1 - mean;
        float vs = d0 * d0 + d1 * d1;
#pragma unroll
        for (int o = 32; o; o >>= 1) vs += __shfl_xor(vs, o);
        const float rstd = rsqrtf(vs * (1.f / 128.f) + 1e-5f);
        float o0 = d0 * rstd * gl0 + bl0;
        float o1 = d1 * rstd * gl1 + bl1;
        x[base + l] = o0;        x[base + l + 64] = o1;
        xb[base + l] = f2b(o0);  xb[base + l + 64] = f2b(o1);
    }
}

extern "C" void kernel_launch(void* const* d_in, const int* in_sizes, int n_in,
                              void* d_out, int out_size, void* d_ws, size_t ws_size,
                              hipStream_t stream)
{
    const float* x_in = (const float*)d_in[0];
    const int*   adj  = (const int*)d_in[1];
    const float* Ws   = (const float*)d_in[2];
    const float* bs   = (const float*)d_in[3];
    const float* As   = (const float*)d_in[4];
    const float* W1   = (const float*)d_in[5];
    const float* b1   = (const float*)d_in[6];
    const float* W2   = (const float*)d_in[7];
    const float* b2   = (const float*)d_in[8];
    const float* g1   = (const float*)d_in[9];
    const float* be1  = (const float*)d_in[10];
    const float* g2   = (const float*)d_in[11];
    const float* be2  = (const float*)d_in[12];
    const float* Wo   = (const float*)d_in[13];
    const float* bo   = (const float*)d_in[14];
    float* out = (float*)d_out;

    char* wsb = (char*)d_ws;
    u16*   maskTb = (u16*)wsb;                        //   0: 2 MB
    float* xc     = (float*)(wsb + (2L << 20));       //   2: 16 MB
    float* y      = (float*)(wsb + (18L << 20));      //  18: 16 MB
    float* CtAll  = (float*)(wsb + (66L << 20));      //  66: 32 MB [L][16][Nn][F]
    u16*   xb     = (u16*)(wsb + (98L << 20));        //  98: 8 MB
    u16*   xrb    = (u16*)(wsb + (106L << 20));       // 106: 8 MB
    u16*   Wob    = (u16*)(wsb + (114L << 20));       // 114: 16 MB
    float* part   = (float*)(wsb + (130L << 20));     // 130: 2 MB
    u16*   xTh    = (u16*)(wsb + (132L << 20));       // 132: 8 MB
    u16*   xTl    = (u16*)(wsb + (140L << 20));       // 140: 8 MB
    u16*   AsTb   = (u16*)(wsb + (148L << 20));       // 148: 16 MB [LH][n][e2]
    u16*   WsTb   = (u16*)(wsb + (164L << 20));       // 164: 2 MB [LH][f][e]
    char*  S      = wsb + (166L << 20);
    int*   degi   = (int*)S;                          // 4 KB
    float* xsp    = (float*)(S + (4L << 10));         // 256 KB [b][16][128]
    float* hsum   = (float*)(S + (260L << 10));       // 128 KB
    float* d12all = (float*)(S + (388L << 10));       // 256 KB
    u16*   W1b    = (u16*)(S + (644L << 10));         // 512 KB
    u16*   W2b    = (u16*)(S + (1156L << 10));        // 512 KB

    hipMemsetAsync(degi, 0, Nn * sizeof(int), stream);
    hipMemcpyAsync(xc, x_in, sizeof(float) * (long)B_ * Nn * F_,
                   hipMemcpyDeviceToDevice, stream);
    k_maskT<<<dim3(16, 16), 256, 0, stream>>>(adj, maskTb, degi);
    k_cvtW<<<(L_ * FF_ * F_) / 256, 256, 0, stream>>>(W1, W2, W1b, W2b);
    k_cvtWo<<<(OUT_ * KTOT) / (256 * 8), 256, 0, stream>>>(Wo, Wob);
    k_tpb<<<dim3(16, 4, L_ * H_), 256, 0, stream>>>(As, AsTb, 2 * E_, Nn);
    k_tpb<<<dim3(2, 2, L_ * H_), 256, 0, stream>>>(Ws, WsTb, E_, F_);
    k_xpose<<<dim3(16, B_), 256, 0, stream>>>(x_in, xTh, xTl);
    k_xs2<<<dim3(16, B_), 256, 0, stream>>>(x_in, xsp);
    k_d12<<<dim3((2 * H_ * Nn) / 256, L_), 256, 0, stream>>>(As, bs, d12all);
    // CtAll[l][2h+p][n][f] = sum_e AsT[l,h][n][p*128+e] * WsT[l,h][f][e]
    k_mfma<64, 128, false, 0, 1, false, false><<<dim3(16, 1, 64), 256, 0, stream>>>(
        AsTb, 2 * E_, (long)Nn * 2 * E_, WsTb, nullptr, E_, (long)F_ * E_,
        nullptr, CtAll, nullptr, F_, (long)Nn * F_, E_);

    for (int l = 0; l < L_; ++l) {
        const float* Wl  = Ws + (long)l * H_ * E_ * F_;
        const float* bsl = bs + (long)l * H_ * E_;

        // y[b][n][f] = sum_j mask[j][n] x[b][j][f]  (dbuf 2-phase, hi+lo)
        k_mfma<128, 64, true, 0, 0, true, true><<<dim3(32, 2, 8), 256, 0, stream>>>(
            maskTb, Nn, 0L, xTh, xTl, Nn, (long)F_ * Nn,
            nullptr, y, nullptr, F_, (long)Nn * F_, Nn);

        k_hsum<<<(B_ * H_ * E_) / 256, 256, 0, stream>>>(xsp, Wl, bsl, hsum);
        k_score_ln1<<<Nn, 256, 0, stream>>>(
            xc, y, CtAll + (long)l * 16 * Nn * F_, d12all + (long)l * 2 * H_ * Nn,
            degi, hsum, g1 + l * F_, be1 + l * F_, xb);
        // fused FF1+FF2+LN2 (+ transposed hi/lo + xsp, or xrb last layer)
        if (l < L_ - 1)
            k_ff_ln2<false><<<512, 256, 0, stream>>>(
                xb, W1b + (long)l * FF_ * F_, b1 + l * FF_,
                W2b + (long)l * F_ * FF_, b2 + l * F_, xc,
                g2 + l * F_, be2 + l * F_, xTh, xTl, xsp, nullptr);
        else
            k_ff_ln2<true><<<512, 256, 0, stream>>>(
                xb, W1b + (long)l * FF_ * F_, b1 + l * FF_,
                W2b + (long)l * F_ * FF_, b2 + l * F_, xc,
                g2 + l * F_, be2 + l * F_, nullptr, nullptr, nullptr, xrb);
    }

    k_final_mfma<<<256, 256, 0, stream>>>(xrb, Wob, part);
    k_final_reduce<<<(B_ * OUT_) / 256, 256, 0, stream>>>(part, bo, out);
}